// Round 1
// baseline (3890.169 us; speedup 1.0000x reference)
//
#include <hip/hip_runtime.h>
#include <cmath>

// CrAKN fused implementation, fp32.
// Dominant cost: per-layer pair-bias chain bias[N^2,64]@diff_W[64,512] -> mish
// -> (per-head norms) -> @bout_W[512,64] -> mish, fused into one kernel that
// never materializes be[N,N,512] in HBM and updates bias in place.

namespace {

constexpr int kN   = 512;
constexpr int kD   = 64;
constexpr int kH   = 4;
constexpr int kHD  = 128;
constexpr int kHHD = 512;
constexpr int kFB  = 256;
constexpr int kK   = 100;
constexpr float kEps   = 1e-5f;
constexpr float kScale = 0.08838834764831845f; // 1/sqrt(128)

__device__ __forceinline__ float mish_f(float x) {
    // x * tanh(softplus(x)), softplus via logaddexp(x,0) for stability
    float sp = fmaxf(x, 0.0f) + log1pf(expf(-fabsf(x)));
    return x * tanhf(sp);
}

__device__ __forceinline__ void ld4(float* d, const float* s) {
    float4 v = *(const float4*)s;
    d[0] = v.x; d[1] = v.y; d[2] = v.z; d[3] = v.w;
}

// ---------------- embed + LN1, and b0 = amds @ bias_emb ----------------
__global__ __launch_bounds__(64) void embed_kernel(
    const float* __restrict__ nf, const float* __restrict__ amds,
    const float* __restrict__ emb_W, const float* __restrict__ emb_b,
    const float* __restrict__ bemb_W, const float* __restrict__ bemb_b,
    const float* __restrict__ ln1_g, const float* __restrict__ ln1_b,
    float* __restrict__ x, float* __restrict__ b0)
{
    const int n = blockIdx.x;
    const int d = threadIdx.x;
    __shared__ float s_row[kFB];
    #pragma unroll
    for (int r = 0; r < kFB / kD; ++r) s_row[r * kD + d] = nf[n * kFB + r * kD + d];
    __syncthreads();
    float acc = emb_b[d];
    for (int k = 0; k < kFB; ++k) acc = fmaf(s_row[k], emb_W[k * kD + d], acc);
    // LayerNorm over D=64 (one wave)
    float mu = acc;
    #pragma unroll
    for (int off = 32; off > 0; off >>= 1) mu += __shfl_xor(mu, off);
    mu *= (1.0f / kD);
    float dv = acc - mu;
    float var = dv * dv;
    #pragma unroll
    for (int off = 32; off > 0; off >>= 1) var += __shfl_xor(var, off);
    var *= (1.0f / kD);
    x[n * kD + d] = dv * rsqrtf(var + kEps) * ln1_g[d] + ln1_b[d];
    __syncthreads();
    // b0 row
    s_row[d] = amds[n * kK + d];
    if (d < kK - kD) s_row[kD + d] = amds[n * kK + kD + d];
    __syncthreads();
    float bacc = bemb_b[d];
    for (int k = 0; k < kK; ++k) bacc = fmaf(s_row[k], bemb_W[k * kD + d], bacc);
    b0[n * kD + d] = bacc;
}

// ---------------- bias[i,j,d] = b0[j,d] - b0[i,d] ----------------
__global__ __launch_bounds__(256) void bias_init_kernel(
    const float* __restrict__ b0, float4* __restrict__ bias)
{
    int gid = blockIdx.x * 256 + threadIdx.x; // over N*N*16 float4s
    int d4 = gid & 15;
    int j  = (gid >> 4) & (kN - 1);
    int i  = gid >> 13;
    const float4* b4 = (const float4*)b0;
    float4 a = b4[j * 16 + d4];
    float4 c = b4[i * 16 + d4];
    bias[gid] = make_float4(a.x - c.x, a.y - c.y, a.z - c.z, a.w - c.w);
}

// ---------------- qkv = x @ qkv_W[l] + qkv_b[l] ----------------
__global__ __launch_bounds__(256) void qkv_kernel(
    const float* __restrict__ x, const float* __restrict__ W,
    const float* __restrict__ b, float* __restrict__ qkv)
{
    const int n = blockIdx.y;
    const int c = blockIdx.x * 256 + threadIdx.x;
    __shared__ float s_x[kD];
    if (threadIdx.x < kD) s_x[threadIdx.x] = x[n * kD + threadIdx.x];
    __syncthreads();
    float acc = b[c];
    #pragma unroll 8
    for (int d = 0; d < kD; ++d) acc = fmaf(s_x[d], W[d * (3 * kHHD) + c], acc);
    qkv[n * (3 * kHHD) + c] = acc;
}

// ---------------- fused pair-bias chain (the workhorse) ----------------
// Per block: 64 pairs. For each of 8 column-chunks (64 cols of be):
//   be_chunk = bias_tile[64x64] @ diff_W[:,chunk]  (+diff_b, mish)
//   accumulate per-head sum-of-squares (chunk ch -> head ch/2)
//   acc2 += be_chunk @ bout_W[chunk,:]
// Epilogue: bias_tile = mish(acc2 + bout_b) in place; diffs = sqrt(sumsq).
__global__ __launch_bounds__(256) void bias_layer_kernel(
    float* __restrict__ bias, const float* __restrict__ diff_W,
    const float* __restrict__ diff_b, const float* __restrict__ bout_W,
    const float* __restrict__ bout_b, float* __restrict__ diffs)
{
    constexpr int SW = 68; // padded stride (float4-aligned, conflict-light)
    __shared__ float s_bias[64 * SW];
    __shared__ float s_w[64 * SW];
    __shared__ float s_be[64 * SW];
    __shared__ float s_diff[64 * 4];

    const int t  = threadIdx.x;
    const int tx = t & 15;
    const int ty = t >> 4;
    const int p0 = blockIdx.x * 64;      // first pair of this tile
    const int i  = p0 >> 9;              // pair row (same for whole tile)
    const int j0 = p0 & (kN - 1);

    { // load bias tile [64][64]
        const float4* g = (const float4*)(bias + (long)p0 * kD);
        #pragma unroll
        for (int rep = 0; rep < 4; ++rep) {
            int f = rep * 256 + t;
            int row = f >> 4;
            int c4  = f & 15;
            *(float4*)&s_bias[row * SW + c4 * 4] = g[f];
        }
    }
    s_diff[t] = 0.0f;

    float acc2[4][4];
    #pragma unroll
    for (int a = 0; a < 4; ++a)
        #pragma unroll
        for (int b = 0; b < 4; ++b) acc2[a][b] = 0.0f;

    for (int ch = 0; ch < 8; ++ch) {
        __syncthreads(); // prev GEMM2 done with s_w / s_be
        // stage diff_W[k][ch*64 + c] -> s_w[k][c]
        #pragma unroll
        for (int rep = 0; rep < 4; ++rep) {
            int f = rep * 256 + t;
            int k  = f >> 4;
            int c4 = f & 15;
            *(float4*)&s_w[k * SW + c4 * 4] =
                *(const float4*)&diff_W[k * kHHD + ch * 64 + c4 * 4];
        }
        __syncthreads();
        // GEMM1: acc1 = bias_tile @ w1
        float acc1[4][4];
        #pragma unroll
        for (int a = 0; a < 4; ++a)
            #pragma unroll
            for (int b = 0; b < 4; ++b) acc1[a][b] = 0.0f;
        for (int k = 0; k < 64; k += 4) {
            float a[4][4], b[4][4];
            #pragma unroll
            for (int rr = 0; rr < 4; ++rr) ld4(a[rr], &s_bias[(4 * ty + rr) * SW + k]);
            #pragma unroll
            for (int u = 0; u < 4; ++u) ld4(b[u], &s_w[(k + u) * SW + 4 * tx]);
            #pragma unroll
            for (int rr = 0; rr < 4; ++rr)
                #pragma unroll
                for (int cc = 0; cc < 4; ++cc)
                    #pragma unroll
                    for (int u = 0; u < 4; ++u)
                        acc1[rr][cc] = fmaf(a[rr][u], b[u][cc], acc1[rr][cc]);
        }
        // +diff_b, mish, sum of squares, stash be chunk
        float db[4];
        #pragma unroll
        for (int cc = 0; cc < 4; ++cc) db[cc] = diff_b[ch * 64 + 4 * tx + cc];
        float psum[4];
        #pragma unroll
        for (int rr = 0; rr < 4; ++rr) {
            float v0 = mish_f(acc1[rr][0] + db[0]);
            float v1 = mish_f(acc1[rr][1] + db[1]);
            float v2 = mish_f(acc1[rr][2] + db[2]);
            float v3 = mish_f(acc1[rr][3] + db[3]);
            psum[rr] = v0 * v0 + v1 * v1 + v2 * v2 + v3 * v3;
            float4 o = make_float4(v0, v1, v2, v3);
            *(float4*)&s_be[(4 * ty + rr) * SW + 4 * tx] = o;
        }
        // reduce psum across the 16 tx lanes (same-ty lanes are contiguous)
        #pragma unroll
        for (int off = 1; off < 16; off <<= 1) {
            #pragma unroll
            for (int rr = 0; rr < 4; ++rr) psum[rr] += __shfl_xor(psum[rr], off);
        }
        if (tx == 0) {
            int h = ch >> 1;
            #pragma unroll
            for (int rr = 0; rr < 4; ++rr) s_diff[(4 * ty + rr) * 4 + h] += psum[rr];
        }
        __syncthreads(); // GEMM1 s_w reads done; s_be visible
        // stage bout_W[ch*64 + kk][c] -> s_w[kk][c]
        #pragma unroll
        for (int rep = 0; rep < 4; ++rep) {
            int f = rep * 256 + t;
            int kk = f >> 4;
            int c4 = f & 15;
            *(float4*)&s_w[kk * SW + c4 * 4] =
                *(const float4*)&bout_W[(ch * 64 + kk) * kD + c4 * 4];
        }
        __syncthreads();
        // GEMM2: acc2 += be_chunk @ w2
        for (int kk = 0; kk < 64; kk += 4) {
            float a[4][4], b[4][4];
            #pragma unroll
            for (int rr = 0; rr < 4; ++rr) ld4(a[rr], &s_be[(4 * ty + rr) * SW + kk]);
            #pragma unroll
            for (int u = 0; u < 4; ++u) ld4(b[u], &s_w[(kk + u) * SW + 4 * tx]);
            #pragma unroll
            for (int rr = 0; rr < 4; ++rr)
                #pragma unroll
                for (int cc = 0; cc < 4; ++cc)
                    #pragma unroll
                    for (int u = 0; u < 4; ++u)
                        acc2[rr][cc] = fmaf(a[rr][u], b[u][cc], acc2[rr][cc]);
        }
    }
    // epilogue: new bias tile (in place)
    float bb[4];
    #pragma unroll
    for (int cc = 0; cc < 4; ++cc) bb[cc] = bout_b[4 * tx + cc];
    #pragma unroll
    for (int rr = 0; rr < 4; ++rr) {
        float4 o;
        o.x = mish_f(acc2[rr][0] + bb[0]);
        o.y = mish_f(acc2[rr][1] + bb[1]);
        o.z = mish_f(acc2[rr][2] + bb[2]);
        o.w = mish_f(acc2[rr][3] + bb[3]);
        *(float4*)&bias[(long)(p0 + 4 * ty + rr) * kD + 4 * tx] = o;
    }
    { // diffs[h][i][j0+r] = sqrt(sumsq)   (s_diff final writes were pre-barrier)
        int r = t >> 2;
        int h = t & 3;
        diffs[h * (kN * kN) + i * kN + (j0 + r)] = sqrtf(s_diff[r * 4 + h]);
    }
}

// ---------------- logits[h,n,m] = scale*q.k + diffs ----------------
__global__ __launch_bounds__(256) void logits_kernel(
    const float* __restrict__ qkv, const float* __restrict__ diffs,
    float* __restrict__ logits)
{
    constexpr int SW = 68;
    __shared__ float s_q[64 * SW];
    __shared__ float s_k[64 * SW];
    const int t  = threadIdx.x;
    const int tX = t & 15;
    const int tY = t >> 4;
    const int h  = blockIdx.z;
    const int n0 = blockIdx.x * 64;
    const int m0 = blockIdx.y * 64;

    float acc[4][4];
    #pragma unroll
    for (int a = 0; a < 4; ++a)
        #pragma unroll
        for (int b = 0; b < 4; ++b) acc[a][b] = 0.0f;

    for (int dc = 0; dc < 2; ++dc) { // two 64-wide d-chunks of HD=128
        __syncthreads();
        #pragma unroll
        for (int rep = 0; rep < 4; ++rep) {
            int f = rep * 256 + t;
            int row = f >> 4;
            int c4  = f & 15;
            *(float4*)&s_q[row * SW + c4 * 4] =
                *(const float4*)&qkv[(n0 + row) * (3 * kHHD) + h * 384 + dc * 64 + c4 * 4];
            *(float4*)&s_k[row * SW + c4 * 4] =
                *(const float4*)&qkv[(m0 + row) * (3 * kHHD) + h * 384 + 128 + dc * 64 + c4 * 4];
        }
        __syncthreads();
        for (int d = 0; d < 64; d += 4) {
            float a[4][4], b[4][4];
            #pragma unroll
            for (int rr = 0; rr < 4; ++rr) ld4(a[rr], &s_q[(tY + 16 * rr) * SW + d]);
            #pragma unroll
            for (int cc = 0; cc < 4; ++cc) ld4(b[cc], &s_k[(tX + 16 * cc) * SW + d]);
            #pragma unroll
            for (int rr = 0; rr < 4; ++rr)
                #pragma unroll
                for (int cc = 0; cc < 4; ++cc)
                    #pragma unroll
                    for (int u = 0; u < 4; ++u)
                        acc[rr][cc] = fmaf(a[rr][u], b[cc][u], acc[rr][cc]);
        }
    }
    #pragma unroll
    for (int rr = 0; rr < 4; ++rr)
        #pragma unroll
        for (int cc = 0; cc < 4; ++cc) {
            int row = n0 + tY + 16 * rr;
            int col = m0 + tX + 16 * cc;
            long idx = (long)h * (kN * kN) + (long)row * kN + col;
            logits[idx] = acc[rr][cc] * kScale + diffs[idx];
        }
}

// ---------------- softmax over m, per (h,n) row ----------------
__global__ __launch_bounds__(256) void softmax_kernel(float* __restrict__ logits)
{
    const int row = blockIdx.x; // h*N + n
    float* p = logits + (long)row * kN;
    const int t = threadIdx.x;
    float v0 = p[t];
    float v1 = p[t + 256];
    float m = fmaxf(v0, v1);
    #pragma unroll
    for (int off = 32; off > 0; off >>= 1) m = fmaxf(m, __shfl_xor(m, off));
    __shared__ float s_red[4];
    __shared__ float s_sum[4];
    if ((t & 63) == 0) s_red[t >> 6] = m;
    __syncthreads();
    m = fmaxf(fmaxf(s_red[0], s_red[1]), fmaxf(s_red[2], s_red[3]));
    float e0 = expf(v0 - m);
    float e1 = expf(v1 - m);
    float s = e0 + e1;
    #pragma unroll
    for (int off = 32; off > 0; off >>= 1) s += __shfl_xor(s, off);
    if ((t & 63) == 0) s_sum[t >> 6] = s;
    __syncthreads();
    s = (s_sum[0] + s_sum[1]) + (s_sum[2] + s_sum[3]);
    float inv = 1.0f / s;
    p[t] = e0 * inv;
    p[t + 256] = e1 * inv;
}

// ---------------- vals[n, h*128+d] = sum_m attn[h,n,m]*v[m,h,d] ----------------
__global__ __launch_bounds__(256) void attnv_kernel(
    const float* __restrict__ attn, const float* __restrict__ qkv,
    float* __restrict__ vals)
{
    constexpr int SW = 68;
    __shared__ float s_p[64 * SW];
    __shared__ float s_v[64 * SW];
    const int t  = threadIdx.x;
    const int tx = t & 15;
    const int ty = t >> 4;
    const int h  = blockIdx.z;
    const int n0 = blockIdx.x * 64;
    const int d0 = blockIdx.y * 64;

    float acc[4][4];
    #pragma unroll
    for (int a = 0; a < 4; ++a)
        #pragma unroll
        for (int b = 0; b < 4; ++b) acc[a][b] = 0.0f;

    for (int mt = 0; mt < 8; ++mt) {
        const int m0 = mt * 64;
        __syncthreads();
        #pragma unroll
        for (int rep = 0; rep < 4; ++rep) {
            int f = rep * 256 + t;
            int row = f >> 4;
            int c4  = f & 15;
            *(float4*)&s_p[row * SW + c4 * 4] =
                *(const float4*)&attn[(long)h * (kN * kN) + (long)(n0 + row) * kN + m0 + c4 * 4];
            *(float4*)&s_v[row * SW + c4 * 4] =
                *(const float4*)&qkv[(m0 + row) * (3 * kHHD) + h * 384 + 256 + d0 + c4 * 4];
        }
        __syncthreads();
        for (int kk = 0; kk < 64; kk += 4) {
            float a[4][4], b[4][4];
            #pragma unroll
            for (int rr = 0; rr < 4; ++rr) ld4(a[rr], &s_p[(4 * ty + rr) * SW + kk]);
            #pragma unroll
            for (int u = 0; u < 4; ++u) ld4(b[u], &s_v[(kk + u) * SW + 4 * tx]);
            #pragma unroll
            for (int rr = 0; rr < 4; ++rr)
                #pragma unroll
                for (int cc = 0; cc < 4; ++cc)
                    #pragma unroll
                    for (int u = 0; u < 4; ++u)
                        acc[rr][cc] = fmaf(a[rr][u], b[u][cc], acc[rr][cc]);
        }
    }
    #pragma unroll
    for (int rr = 0; rr < 4; ++rr) {
        float4 o = make_float4(acc[rr][0], acc[rr][1], acc[rr][2], acc[rr][3]);
        *(float4*)&vals[(long)(n0 + 4 * ty + rr) * kHHD + h * kHD + d0 + 4 * tx] = o;
    }
}

// ---------------- x = LN2(x + vals@o_W + o_b) ----------------
__global__ __launch_bounds__(64) void oproj_ln_kernel(
    const float* __restrict__ vals, const float* __restrict__ o_W,
    const float* __restrict__ o_b, const float* __restrict__ g2,
    const float* __restrict__ b2, float* __restrict__ x)
{
    const int n = blockIdx.x;
    const int d = threadIdx.x;
    __shared__ float s_v[kHHD];
    #pragma unroll
    for (int r = 0; r < kHHD / kD; ++r) s_v[r * kD + d] = vals[n * kHHD + r * kD + d];
    __syncthreads();
    float acc = o_b[d];
    for (int j = 0; j < kHHD; ++j) acc = fmaf(s_v[j], o_W[j * kD + d], acc);
    float xv = x[n * kD + d] + acc;
    float mu = xv;
    #pragma unroll
    for (int off = 32; off > 0; off >>= 1) mu += __shfl_xor(mu, off);
    mu *= (1.0f / kD);
    float dv = xv - mu;
    float var = dv * dv;
    #pragma unroll
    for (int off = 32; off > 0; off >>= 1) var += __shfl_xor(var, off);
    var *= (1.0f / kD);
    x[n * kD + d] = dv * rsqrtf(var + kEps) * g2[d] + b2[d];
}

// ---------------- out = x @ out_W + out_b ----------------
__global__ __launch_bounds__(64) void final_kernel(
    const float* __restrict__ x, const float* __restrict__ out_W,
    const float* __restrict__ out_b, float* __restrict__ out)
{
    const int n = blockIdx.x * 64 + threadIdx.x;
    float acc = out_b[0];
    #pragma unroll
    for (int d = 0; d < kD; ++d) acc = fmaf(x[n * kD + d], out_W[d], acc);
    out[n] = acc;
}

} // anonymous namespace

extern "C" void kernel_launch(void* const* d_in, const int* in_sizes, int n_in,
                              void* d_out, int out_size, void* d_ws, size_t ws_size,
                              hipStream_t stream)
{
    (void)in_sizes; (void)n_in; (void)out_size; (void)ws_size;

    const float* nf     = (const float*)d_in[0];
    const float* amds   = (const float*)d_in[1];
    const float* emb_W  = (const float*)d_in[2];
    const float* emb_b  = (const float*)d_in[3];
    const float* bemb_W = (const float*)d_in[4];
    const float* bemb_b = (const float*)d_in[5];
    const float* ln1_g  = (const float*)d_in[6];
    const float* ln1_b  = (const float*)d_in[7];
    const float* ln2_g  = (const float*)d_in[8];
    const float* ln2_b  = (const float*)d_in[9];
    const float* qkv_W  = (const float*)d_in[10];
    const float* qkv_b  = (const float*)d_in[11];
    const float* diff_W = (const float*)d_in[12];
    const float* diff_b = (const float*)d_in[13];
    const float* o_W    = (const float*)d_in[14];
    const float* o_b    = (const float*)d_in[15];
    const float* bout_W = (const float*)d_in[16];
    const float* bout_b = (const float*)d_in[17];
    const float* out_W  = (const float*)d_in[18];
    const float* out_b  = (const float*)d_in[19];

    float* ws = (float*)d_ws;
    float* ws_x      = ws;                   // 512*64      = 32768
    float* ws_b0     = ws_x + 32768;         // 512*64      = 32768
    float* ws_qkv    = ws_b0 + 32768;        // 512*1536    = 786432
    float* ws_vals   = ws_qkv + 786432;      // 512*512     = 262144
    float* ws_diffs  = ws_vals + 262144;     // 4*512*512   = 1048576
    float* ws_logits = ws_diffs + 1048576;   // 4*512*512   = 1048576
    float* ws_bias   = ws_logits + 1048576;  // 512*512*64  = 16777216  (~80 MB total)

    embed_kernel<<<kN, kD, 0, stream>>>(nf, amds, emb_W, emb_b, bemb_W, bemb_b,
                                        ln1_g, ln1_b, ws_x, ws_b0);
    bias_init_kernel<<<(kN * kN * kD / 4) / 256, 256, 0, stream>>>(
        ws_b0, (float4*)ws_bias);

    for (int l = 0; l < 4; ++l) {
        qkv_kernel<<<dim3(6, kN), 256, 0, stream>>>(
            ws_x, qkv_W + l * kD * (3 * kHHD), qkv_b + l * (3 * kHHD), ws_qkv);
        bias_layer_kernel<<<kN * kN / 64, 256, 0, stream>>>(
            ws_bias, diff_W + l * kD * kHHD, diff_b + l * kHHD,
            bout_W + l * kHHD * kD, bout_b + l * kD, ws_diffs);
        logits_kernel<<<dim3(8, 8, kH), 256, 0, stream>>>(ws_qkv, ws_diffs, ws_logits);
        softmax_kernel<<<kH * kN, 256, 0, stream>>>(ws_logits);
        attnv_kernel<<<dim3(8, 2, kH), 256, 0, stream>>>(ws_logits, ws_qkv, ws_vals);
        oproj_ln_kernel<<<kN, kD, 0, stream>>>(
            ws_vals, o_W + l * kHHD * kD, o_b + l * kD, ln2_g, ln2_b, ws_x);
    }
    final_kernel<<<kN / kD, kD, 0, stream>>>(ws_x, out_W, out_b, (float*)d_out);
}

// Round 2
// 1211.430 us; speedup vs baseline: 3.2112x; 3.2112x over previous
//
#include <hip/hip_runtime.h>
#include <cmath>

// CrAKN fused implementation.
// R2: bias chain (the 137 GFLOP dominant cost) moved from fp32 VALU (33 TF
// effective) to bf16x3 split-precision MFMA. Weights pre-transposed+split to
// bf16 hi/lo planes once per launch; bias/be tiles staged through LDS in MFMA
// fragment layout. Mish via exp/rcp identity instead of libm tanh.

namespace {

constexpr int kN   = 512;
constexpr int kD   = 64;
constexpr int kH   = 4;
constexpr int kHD  = 128;
constexpr int kHHD = 512;
constexpr int kFB  = 256;
constexpr int kK   = 100;
constexpr float kEps   = 1e-5f;
constexpr float kScale = 0.08838834764831845f; // 1/sqrt(128)

typedef unsigned short u16;
typedef short bf16x8 __attribute__((ext_vector_type(8)));
typedef float f32x4 __attribute__((ext_vector_type(4)));

// mish(x) = x*tanh(softplus(x)) = x * n/(n+2), n = e*(e+2), e = exp(x).
// Exact algebraic identity; clamp avoids e^2 overflow (mish(x)=x to 1e-13 for x>15).
__device__ __forceinline__ float mish_f(float x) {
    float e = __expf(fminf(x, 15.0f));
    float n = e * (e + 2.0f);
    return x * n * __builtin_amdgcn_rcpf(n + 2.0f);
}

__device__ __forceinline__ u16 bf16_rne(float f) {
    unsigned int u = __float_as_uint(f);
    u = u + 0x7FFFu + ((u >> 16) & 1u);
    return (u16)(u >> 16);
}
__device__ __forceinline__ void bf16_split(float f, u16& h, u16& l) {
    h = bf16_rne(f);
    float fh = __uint_as_float((unsigned int)h << 16);
    l = bf16_rne(f - fh);
}

__device__ __forceinline__ void ld4(float* d, const float* s) {
    float4 v = *(const float4*)s;
    d[0] = v.x; d[1] = v.y; d[2] = v.z; d[3] = v.w;
}

// ---------------- embed + LN1, and b0 = amds @ bias_emb ----------------
__global__ __launch_bounds__(64) void embed_kernel(
    const float* __restrict__ nf, const float* __restrict__ amds,
    const float* __restrict__ emb_W, const float* __restrict__ emb_b,
    const float* __restrict__ bemb_W, const float* __restrict__ bemb_b,
    const float* __restrict__ ln1_g, const float* __restrict__ ln1_b,
    float* __restrict__ x, float* __restrict__ b0)
{
    const int n = blockIdx.x;
    const int d = threadIdx.x;
    __shared__ float s_row[kFB];
    #pragma unroll
    for (int r = 0; r < kFB / kD; ++r) s_row[r * kD + d] = nf[n * kFB + r * kD + d];
    __syncthreads();
    float acc = emb_b[d];
    for (int k = 0; k < kFB; ++k) acc = fmaf(s_row[k], emb_W[k * kD + d], acc);
    float mu = acc;
    #pragma unroll
    for (int off = 32; off > 0; off >>= 1) mu += __shfl_xor(mu, off);
    mu *= (1.0f / kD);
    float dv = acc - mu;
    float var = dv * dv;
    #pragma unroll
    for (int off = 32; off > 0; off >>= 1) var += __shfl_xor(var, off);
    var *= (1.0f / kD);
    x[n * kD + d] = dv * rsqrtf(var + kEps) * ln1_g[d] + ln1_b[d];
    __syncthreads();
    s_row[d] = amds[n * kK + d];
    if (d < kK - kD) s_row[kD + d] = amds[n * kK + kD + d];
    __syncthreads();
    float bacc = bemb_b[d];
    for (int k = 0; k < kK; ++k) bacc = fmaf(s_row[k], bemb_W[k * kD + d], bacc);
    b0[n * kD + d] = bacc;
}

// ---------------- bias[i,j,d] = b0[j,d] - b0[i,d] ----------------
__global__ __launch_bounds__(256) void bias_init_kernel(
    const float* __restrict__ b0, float4* __restrict__ bias)
{
    int gid = blockIdx.x * 256 + threadIdx.x;
    int d4 = gid & 15;
    int j  = (gid >> 4) & (kN - 1);
    int i  = gid >> 13;
    const float4* b4 = (const float4*)b0;
    float4 a = b4[j * 16 + d4];
    float4 c = b4[i * 16 + d4];
    bias[gid] = make_float4(a.x - c.x, a.y - c.y, a.z - c.z, a.w - c.w);
}

// ---------------- per-launch weight prep: transpose + bf16 hi/lo split ------
// dWt[l][n][k]  (n<512, k<64)  from diff_W[l][k][n]
// boutWt[l][d][k] (d<64, k<512) from bout_W[l][k][d]
__global__ __launch_bounds__(256) void prep_weights_kernel(
    const float* __restrict__ diff_W, const float* __restrict__ bout_W,
    u16* __restrict__ dWt_hi, u16* __restrict__ dWt_lo,
    u16* __restrict__ boutWt_hi, u16* __restrict__ boutWt_lo)
{
    int gid = blockIdx.x * 256 + threadIdx.x; // 2 * 4 * 32768
    if (gid < 4 * 32768) {
        int e = gid;
        int l = e >> 15;
        int r = e & 32767;
        int k = r >> 9;
        int n = r & 511;
        u16 h, lo;
        bf16_split(diff_W[e], h, lo);
        int w = l * 32768 + n * 64 + k;
        dWt_hi[w] = h; dWt_lo[w] = lo;
    } else {
        int e = gid - 4 * 32768;
        int l = e >> 15;
        int r = e & 32767;
        int k = r >> 6;
        int d = r & 63;
        u16 h, lo;
        bf16_split(bout_W[e], h, lo);
        int w = l * 32768 + d * 512 + k;
        boutWt_hi[w] = h; boutWt_lo[w] = lo;
    }
}

// ---------------- qkv = x @ qkv_W[l] + qkv_b[l] ----------------
__global__ __launch_bounds__(256) void qkv_kernel(
    const float* __restrict__ x, const float* __restrict__ W,
    const float* __restrict__ b, float* __restrict__ qkv)
{
    const int n = blockIdx.y;
    const int c = blockIdx.x * 256 + threadIdx.x;
    __shared__ float s_x[kD];
    if (threadIdx.x < kD) s_x[threadIdx.x] = x[n * kD + threadIdx.x];
    __syncthreads();
    float acc = b[c];
    #pragma unroll 8
    for (int d = 0; d < kD; ++d) acc = fmaf(s_x[d], W[d * (3 * kHHD) + c], acc);
    qkv[n * (3 * kHHD) + c] = acc;
}

// ---------------- fused pair-bias chain, MFMA bf16x3 ----------------
// Block = 64 pairs. 8 chunks of 64 be-columns:
//   GEMM1: be_chunk[64x64] = bias_tile[64x64(K)] @ diff_W chunk   (bf16x3 MFMA)
//   mish, per-head sum-of-squares, split be -> LDS
//   GEMM2: acc2[64x64] += be_chunk @ bout_W chunk                 (bf16x3 MFMA)
// Wave w owns output col-strip [16w,16w+16), 4 row-tiles of 16.
__global__ __launch_bounds__(256, 4) void bias_layer_mfma(
    float* __restrict__ bias,
    const u16* __restrict__ dWt_hi, const u16* __restrict__ dWt_lo,
    const u16* __restrict__ boutWt_hi, const u16* __restrict__ boutWt_lo,
    const float* __restrict__ diff_b, const float* __restrict__ bout_b,
    float* __restrict__ diffs)
{
    constexpr int SB = 72; // bf16 LDS row stride (144 B, 16B-aligned)
    __shared__ u16 s_bh[64 * SB]; // bias tile hi
    __shared__ u16 s_bl[64 * SB]; // bias tile lo
    __shared__ u16 s_eh[64 * SB]; // be chunk hi
    __shared__ u16 s_el[64 * SB]; // be chunk lo
    __shared__ float s_dp[4][64][4]; // per-wave diff partials [wave][row][head]

    const int t    = threadIdx.x;
    const int w    = t >> 6;       // wave 0..3 -> col-strip
    const int lane = t & 63;
    const int q    = lane >> 4;    // quad
    const int c    = lane & 15;
    const int p0   = blockIdx.x * 64;
    const int i    = p0 >> 9;
    const int j0   = p0 & (kN - 1);

    // prologue: load bias tile [64 rows x 64 k], split to bf16 planes
    {
        const float4* g = (const float4*)(bias + (long)p0 * kD);
        #pragma unroll
        for (int rep = 0; rep < 4; ++rep) {
            int idx4 = rep * 256 + t;      // 1024 float4s
            int row  = idx4 >> 4;
            int c4   = idx4 & 15;
            float4 v = g[idx4];
            u16 h0, l0, h1, l1, h2, l2, h3, l3;
            bf16_split(v.x, h0, l0); bf16_split(v.y, h1, l1);
            bf16_split(v.z, h2, l2); bf16_split(v.w, h3, l3);
            int base = row * SB + c4 * 4;
            *(uint2*)&s_bh[base] = make_uint2((unsigned)h0 | ((unsigned)h1 << 16),
                                              (unsigned)h2 | ((unsigned)h3 << 16));
            *(uint2*)&s_bl[base] = make_uint2((unsigned)l0 | ((unsigned)l1 << 16),
                                              (unsigned)l2 | ((unsigned)l3 << 16));
        }
        float* dp = (float*)s_dp;
        #pragma unroll
        for (int rep = 0; rep < 4; ++rep) dp[rep * 256 + t] = 0.0f;
    }

    f32x4 acc2[4];
    #pragma unroll
    for (int mt = 0; mt < 4; ++mt) acc2[mt] = (f32x4)0.0f;

    const float db = diff_b[w * 16 + c];        // will index + ch*64 below
    const u16* dh_base = dWt_hi + (w * 16 + c) * 64;
    const u16* dl_base = dWt_lo + (w * 16 + c) * 64;
    const u16* oh_base = boutWt_hi + (w * 16 + c) * 512;
    const u16* ol_base = boutWt_lo + (w * 16 + c) * 512;

    for (int ch = 0; ch < 8; ++ch) {
        __syncthreads(); // prologue writes visible (ch=0) / prev GEMM2 reads done

        // ---- GEMM1: bias_tile @ dW chunk -> acc1 (cols w*16+c, rows mt*16+4q+r)
        f32x4 acc1[4];
        #pragma unroll
        for (int mt = 0; mt < 4; ++mt) acc1[mt] = (f32x4)0.0f;
        const u16* dh = dh_base + (long)(ch * 64) * 64;
        const u16* dl = dl_base + (long)(ch * 64) * 64;
        #pragma unroll
        for (int s = 0; s < 2; ++s) {
            bf16x8 wbh = *(const bf16x8*)(dh + s * 32 + q * 8);
            bf16x8 wbl = *(const bf16x8*)(dl + s * 32 + q * 8);
            #pragma unroll
            for (int mt = 0; mt < 4; ++mt) {
                int ab = (mt * 16 + c) * SB + s * 32 + q * 8;
                bf16x8 ah = *(const bf16x8*)&s_bh[ab];
                bf16x8 al = *(const bf16x8*)&s_bl[ab];
                acc1[mt] = __builtin_amdgcn_mfma_f32_16x16x32_bf16(ah, wbh, acc1[mt], 0, 0, 0);
                acc1[mt] = __builtin_amdgcn_mfma_f32_16x16x32_bf16(al, wbh, acc1[mt], 0, 0, 0);
                acc1[mt] = __builtin_amdgcn_mfma_f32_16x16x32_bf16(ah, wbl, acc1[mt], 0, 0, 0);
            }
        }

        // ---- mish + split -> be planes; per-row sum of squares
        const float dbc = diff_b[ch * 64 + w * 16 + c];
        float ps[4][4];
        #pragma unroll
        for (int mt = 0; mt < 4; ++mt) {
            #pragma unroll
            for (int r = 0; r < 4; ++r) {
                float v = mish_f(acc1[mt][r] + dbc);
                ps[mt][r] = v * v;
                u16 h, lo;
                bf16_split(v, h, lo);
                int eb = (mt * 16 + 4 * q + r) * SB + w * 16 + c;
                s_eh[eb] = h;
                s_el[eb] = lo;
            }
        }
        #pragma unroll
        for (int mt = 0; mt < 4; ++mt)
            #pragma unroll
            for (int r = 0; r < 4; ++r) {
                #pragma unroll
                for (int off = 1; off < 16; off <<= 1)
                    ps[mt][r] += __shfl_xor(ps[mt][r], off);
            }
        if (c == 0) {
            int h = ch >> 1;
            #pragma unroll
            for (int mt = 0; mt < 4; ++mt)
                #pragma unroll
                for (int r = 0; r < 4; ++r)
                    s_dp[w][mt * 16 + 4 * q + r][h] += ps[mt][r];
        }

        __syncthreads(); // be planes visible

        // ---- GEMM2: be_chunk @ bout_W chunk -> acc2 (cols d = w*16+c)
        const u16* oh = oh_base + ch * 64;
        const u16* ol = ol_base + ch * 64;
        #pragma unroll
        for (int s = 0; s < 2; ++s) {
            bf16x8 wbh = *(const bf16x8*)(oh + s * 32 + q * 8);
            bf16x8 wbl = *(const bf16x8*)(ol + s * 32 + q * 8);
            #pragma unroll
            for (int mt = 0; mt < 4; ++mt) {
                int ab = (mt * 16 + c) * SB + s * 32 + q * 8;
                bf16x8 ah = *(const bf16x8*)&s_eh[ab];
                bf16x8 al = *(const bf16x8*)&s_el[ab];
                acc2[mt] = __builtin_amdgcn_mfma_f32_16x16x32_bf16(ah, wbh, acc2[mt], 0, 0, 0);
                acc2[mt] = __builtin_amdgcn_mfma_f32_16x16x32_bf16(al, wbh, acc2[mt], 0, 0, 0);
                acc2[mt] = __builtin_amdgcn_mfma_f32_16x16x32_bf16(ah, wbl, acc2[mt], 0, 0, 0);
            }
        }
    }
    (void)db;

    // ---- epilogue: bias tile in place, diffs
    const float bb = bout_b[w * 16 + c];
    #pragma unroll
    for (int mt = 0; mt < 4; ++mt) {
        #pragma unroll
        for (int r = 0; r < 4; ++r) {
            float v = mish_f(acc2[mt][r] + bb);
            bias[(long)(p0 + mt * 16 + 4 * q + r) * kD + w * 16 + c] = v;
        }
    }
    {
        int row = t >> 2;
        int h2  = t & 3;
        float sum = s_dp[0][row][h2] + s_dp[1][row][h2]
                  + s_dp[2][row][h2] + s_dp[3][row][h2];
        diffs[h2 * (kN * kN) + i * kN + (j0 + row)] = sqrtf(sum);
    }
}

// ---------------- logits[h,n,m] = scale*q.k + diffs ----------------
__global__ __launch_bounds__(256) void logits_kernel(
    const float* __restrict__ qkv, const float* __restrict__ diffs,
    float* __restrict__ logits)
{
    constexpr int SW = 68;
    __shared__ float s_q[64 * SW];
    __shared__ float s_k[64 * SW];
    const int t  = threadIdx.x;
    const int tX = t & 15;
    const int tY = t >> 4;
    const int h  = blockIdx.z;
    const int n0 = blockIdx.x * 64;
    const int m0 = blockIdx.y * 64;

    float acc[4][4];
    #pragma unroll
    for (int a = 0; a < 4; ++a)
        #pragma unroll
        for (int b = 0; b < 4; ++b) acc[a][b] = 0.0f;

    for (int dc = 0; dc < 2; ++dc) {
        __syncthreads();
        #pragma unroll
        for (int rep = 0; rep < 4; ++rep) {
            int f = rep * 256 + t;
            int row = f >> 4;
            int c4  = f & 15;
            *(float4*)&s_q[row * SW + c4 * 4] =
                *(const float4*)&qkv[(n0 + row) * (3 * kHHD) + h * 384 + dc * 64 + c4 * 4];
            *(float4*)&s_k[row * SW + c4 * 4] =
                *(const float4*)&qkv[(m0 + row) * (3 * kHHD) + h * 384 + 128 + dc * 64 + c4 * 4];
        }
        __syncthreads();
        for (int d = 0; d < 64; d += 4) {
            float a[4][4], b[4][4];
            #pragma unroll
            for (int rr = 0; rr < 4; ++rr) ld4(a[rr], &s_q[(tY + 16 * rr) * SW + d]);
            #pragma unroll
            for (int cc = 0; cc < 4; ++cc) ld4(b[cc], &s_k[(tX + 16 * cc) * SW + d]);
            #pragma unroll
            for (int rr = 0; rr < 4; ++rr)
                #pragma unroll
                for (int cc = 0; cc < 4; ++cc)
                    #pragma unroll
                    for (int u = 0; u < 4; ++u)
                        acc[rr][cc] = fmaf(a[rr][u], b[cc][u], acc[rr][cc]);
        }
    }
    #pragma unroll
    for (int rr = 0; rr < 4; ++rr)
        #pragma unroll
        for (int cc = 0; cc < 4; ++cc) {
            int row = n0 + tY + 16 * rr;
            int col = m0 + tX + 16 * cc;
            long idx = (long)h * (kN * kN) + (long)row * kN + col;
            logits[idx] = acc[rr][cc] * kScale + diffs[idx];
        }
}

// ---------------- softmax over m, per (h,n) row ----------------
__global__ __launch_bounds__(256) void softmax_kernel(float* __restrict__ logits)
{
    const int row = blockIdx.x;
    float* p = logits + (long)row * kN;
    const int t = threadIdx.x;
    float v0 = p[t];
    float v1 = p[t + 256];
    float m = fmaxf(v0, v1);
    #pragma unroll
    for (int off = 32; off > 0; off >>= 1) m = fmaxf(m, __shfl_xor(m, off));
    __shared__ float s_red[4];
    __shared__ float s_sum[4];
    if ((t & 63) == 0) s_red[t >> 6] = m;
    __syncthreads();
    m = fmaxf(fmaxf(s_red[0], s_red[1]), fmaxf(s_red[2], s_red[3]));
    float e0 = expf(v0 - m);
    float e1 = expf(v1 - m);
    float s = e0 + e1;
    #pragma unroll
    for (int off = 32; off > 0; off >>= 1) s += __shfl_xor(s, off);
    if ((t & 63) == 0) s_sum[t >> 6] = s;
    __syncthreads();
    s = (s_sum[0] + s_sum[1]) + (s_sum[2] + s_sum[3]);
    float inv = 1.0f / s;
    p[t] = e0 * inv;
    p[t + 256] = e1 * inv;
}

// ---------------- vals[n, h*128+d] = sum_m attn[h,n,m]*v[m,h,d] ----------------
__global__ __launch_bounds__(256) void attnv_kernel(
    const float* __restrict__ attn, const float* __restrict__ qkv,
    float* __restrict__ vals)
{
    constexpr int SW = 68;
    __shared__ float s_p[64 * SW];
    __shared__ float s_v[64 * SW];
    const int t  = threadIdx.x;
    const int tx = t & 15;
    const int ty = t >> 4;
    const int h  = blockIdx.z;
    const int n0 = blockIdx.x * 64;
    const int d0 = blockIdx.y * 64;

    float acc[4][4];
    #pragma unroll
    for (int a = 0; a < 4; ++a)
        #pragma unroll
        for (int b = 0; b < 4; ++b) acc[a][b] = 0.0f;

    for (int mt = 0; mt < 8; ++mt) {
        const int m0 = mt * 64;
        __syncthreads();
        #pragma unroll
        for (int rep = 0; rep < 4; ++rep) {
            int f = rep * 256 + t;
            int row = f >> 4;
            int c4  = f & 15;
            *(float4*)&s_p[row * SW + c4 * 4] =
                *(const float4*)&attn[(long)h * (kN * kN) + (long)(n0 + row) * kN + m0 + c4 * 4];
            *(float4*)&s_v[row * SW + c4 * 4] =
                *(const float4*)&qkv[(m0 + row) * (3 * kHHD) + h * 384 + 256 + d0 + c4 * 4];
        }
        __syncthreads();
        for (int kk = 0; kk < 64; kk += 4) {
            float a[4][4], b[4][4];
            #pragma unroll
            for (int rr = 0; rr < 4; ++rr) ld4(a[rr], &s_p[(4 * ty + rr) * SW + kk]);
            #pragma unroll
            for (int u = 0; u < 4; ++u) ld4(b[u], &s_v[(kk + u) * SW + 4 * tx]);
            #pragma unroll
            for (int rr = 0; rr < 4; ++rr)
                #pragma unroll
                for (int cc = 0; cc < 4; ++cc)
                    #pragma unroll
                    for (int u = 0; u < 4; ++u)
                        acc[rr][cc] = fmaf(a[rr][u], b[u][cc], acc[rr][cc]);
        }
    }
    #pragma unroll
    for (int rr = 0; rr < 4; ++rr) {
        float4 o = make_float4(acc[rr][0], acc[rr][1], acc[rr][2], acc[rr][3]);
        *(float4*)&vals[(long)(n0 + 4 * ty + rr) * kHHD + h * kHD + d0 + 4 * tx] = o;
    }
}

// ---------------- x = LN2(x + vals@o_W + o_b) ----------------
__global__ __launch_bounds__(64) void oproj_ln_kernel(
    const float* __restrict__ vals, const float* __restrict__ o_W,
    const float* __restrict__ o_b, const float* __restrict__ g2,
    const float* __restrict__ b2, float* __restrict__ x)
{
    const int n = blockIdx.x;
    const int d = threadIdx.x;
    __shared__ float s_v[kHHD];
    #pragma unroll
    for (int r = 0; r < kHHD / kD; ++r) s_v[r * kD + d] = vals[n * kHHD + r * kD + d];
    __syncthreads();
    float acc = o_b[d];
    for (int j = 0; j < kHHD; ++j) acc = fmaf(s_v[j], o_W[j * kD + d], acc);
    float xv = x[n * kD + d] + acc;
    float mu = xv;
    #pragma unroll
    for (int off = 32; off > 0; off >>= 1) mu += __shfl_xor(mu, off);
    mu *= (1.0f / kD);
    float dv = xv - mu;
    float var = dv * dv;
    #pragma unroll
    for (int off = 32; off > 0; off >>= 1) var += __shfl_xor(var, off);
    var *= (1.0f / kD);
    x[n * kD + d] = dv * rsqrtf(var + kEps) * g2[d] + b2[d];
}

// ---------------- out = x @ out_W + out_b ----------------
__global__ __launch_bounds__(64) void final_kernel(
    const float* __restrict__ x, const float* __restrict__ out_W,
    const float* __restrict__ out_b, float* __restrict__ out)
{
    const int n = blockIdx.x * 64 + threadIdx.x;
    float acc = out_b[0];
    #pragma unroll
    for (int d = 0; d < kD; ++d) acc = fmaf(x[n * kD + d], out_W[d], acc);
    out[n] = acc;
}

} // anonymous namespace

extern "C" void kernel_launch(void* const* d_in, const int* in_sizes, int n_in,
                              void* d_out, int out_size, void* d_ws, size_t ws_size,
                              hipStream_t stream)
{
    (void)in_sizes; (void)n_in; (void)out_size; (void)ws_size;

    const float* nf     = (const float*)d_in[0];
    const float* amds   = (const float*)d_in[1];
    const float* emb_W  = (const float*)d_in[2];
    const float* emb_b  = (const float*)d_in[3];
    const float* bemb_W = (const float*)d_in[4];
    const float* bemb_b = (const float*)d_in[5];
    const float* ln1_g  = (const float*)d_in[6];
    const float* ln1_b  = (const float*)d_in[7];
    const float* ln2_g  = (const float*)d_in[8];
    const float* ln2_b  = (const float*)d_in[9];
    const float* qkv_W  = (const float*)d_in[10];
    const float* qkv_b  = (const float*)d_in[11];
    const float* diff_W = (const float*)d_in[12];
    const float* diff_b = (const float*)d_in[13];
    const float* o_W    = (const float*)d_in[14];
    const float* o_b    = (const float*)d_in[15];
    const float* bout_W = (const float*)d_in[16];
    const float* bout_b = (const float*)d_in[17];
    const float* out_W  = (const float*)d_in[18];
    const float* out_b  = (const float*)d_in[19];

    float* ws = (float*)d_ws;
    float* ws_x      = ws;                   // 512*64
    float* ws_b0     = ws_x + 32768;         // 512*64
    float* ws_qkv    = ws_b0 + 32768;        // 512*1536
    float* ws_vals   = ws_qkv + 786432;      // 512*512
    float* ws_diffs  = ws_vals + 262144;     // 4*512*512
    float* ws_logits = ws_diffs + 1048576;   // 4*512*512
    float* ws_bias   = ws_logits + 1048576;  // 512*512*64
    u16*   ws_u      = (u16*)(ws_bias + 16777216); // +1 MB of bf16 planes
    u16* dWt_hi    = ws_u;                   // 4*512*64
    u16* dWt_lo    = dWt_hi + 131072;
    u16* boutWt_hi = dWt_lo + 131072;        // 4*64*512
    u16* boutWt_lo = boutWt_hi + 131072;

    embed_kernel<<<kN, kD, 0, stream>>>(nf, amds, emb_W, emb_b, bemb_W, bemb_b,
                                        ln1_g, ln1_b, ws_x, ws_b0);
    bias_init_kernel<<<(kN * kN * kD / 4) / 256, 256, 0, stream>>>(
        ws_b0, (float4*)ws_bias);
    prep_weights_kernel<<<(2 * 4 * 32768) / 256, 256, 0, stream>>>(
        diff_W, bout_W, dWt_hi, dWt_lo, boutWt_hi, boutWt_lo);

    for (int l = 0; l < 4; ++l) {
        qkv_kernel<<<dim3(6, kN), 256, 0, stream>>>(
            ws_x, qkv_W + l * kD * (3 * kHHD), qkv_b + l * (3 * kHHD), ws_qkv);
        bias_layer_mfma<<<kN * kN / 64, 256, 0, stream>>>(
            ws_bias, dWt_hi + l * 32768, dWt_lo + l * 32768,
            boutWt_hi + l * 32768, boutWt_lo + l * 32768,
            diff_b + l * kHHD, bout_b + l * kD, ws_diffs);
        logits_kernel<<<dim3(8, 8, kH), 256, 0, stream>>>(ws_qkv, ws_diffs, ws_logits);
        softmax_kernel<<<kH * kN, 256, 0, stream>>>(ws_logits);
        attnv_kernel<<<dim3(8, 2, kH), 256, 0, stream>>>(ws_logits, ws_qkv, ws_vals);
        oproj_ln_kernel<<<kN, kD, 0, stream>>>(
            ws_vals, o_W + l * kHHD * kD, o_b + l * kD, ln2_g, ln2_b, ws_x);
    }
    final_kernel<<<kN / kD, kD, 0, stream>>>(ws_x, out_W, out_b, (float*)d_out);
}

// Round 3
// 1192.414 us; speedup vs baseline: 3.2624x; 1.0159x over previous
//
#include <hip/hip_runtime.h>
#include <hip/hip_bf16.h>
#include <cmath>

// CrAKN fused implementation.
// R3: bias_layer_mfma restructured: A-frags (bias tile) hoisted to VGPRs for
// the whole K-loop (invariant across chunks), per-head register psum with
// one flush per head, packed bf16 converts (v_cvt_pk_bf16_f32), and
// double-buffered be LDS chunk (1 barrier/chunk). B operands (weights) load
// straight from global/L1 as MFMA fragments.

namespace {

constexpr int kN   = 512;
constexpr int kD   = 64;
constexpr int kH   = 4;
constexpr int kHD  = 128;
constexpr int kHHD = 512;
constexpr int kFB  = 256;
constexpr int kK   = 100;
constexpr float kEps   = 1e-5f;
constexpr float kScale = 0.08838834764831845f; // 1/sqrt(128)

typedef unsigned short u16;
typedef unsigned int u32;
typedef short bf16x8 __attribute__((ext_vector_type(8)));
typedef float f32x4 __attribute__((ext_vector_type(4)));

// mish(x) = x*tanh(softplus(x)) = x * n/(n+2), n = e*(e+2), e = exp(x).
__device__ __forceinline__ float mish_f(float x) {
    float e = __expf(fminf(x, 15.0f));
    float n = e * (e + 2.0f);
    return x * n * __builtin_amdgcn_rcpf(n + 2.0f);
}

__device__ __forceinline__ u32 pk_bf16(float a, float b) {
    union { __hip_bfloat162 v; u32 u; } cv;
    cv.v = __float22bfloat162_rn(make_float2(a, b));
    return cv.u; // a in low 16, b in high 16
}
// split a,b into bf16 hi pair + bf16 lo (residual) pair
__device__ __forceinline__ void split2(float a, float b, u32& hi, u32& lo) {
    hi = pk_bf16(a, b);
    float fa = __uint_as_float(hi << 16);
    float fb = __uint_as_float(hi & 0xFFFF0000u);
    lo = pk_bf16(a - fa, b - fb);
}
__device__ __forceinline__ bf16x8 mk8(u32 a, u32 b, u32 c, u32 d) {
    union { u32 w[4]; bf16x8 v; } cv;
    cv.w[0] = a; cv.w[1] = b; cv.w[2] = c; cv.w[3] = d;
    return cv.v;
}

__device__ __forceinline__ u16 bf16_rne(float f) {
    u32 u = __float_as_uint(f);
    u = u + 0x7FFFu + ((u >> 16) & 1u);
    return (u16)(u >> 16);
}
__device__ __forceinline__ void bf16_split(float f, u16& h, u16& l) {
    h = bf16_rne(f);
    float fh = __uint_as_float((u32)h << 16);
    l = bf16_rne(f - fh);
}

__device__ __forceinline__ void ld4(float* d, const float* s) {
    float4 v = *(const float4*)s;
    d[0] = v.x; d[1] = v.y; d[2] = v.z; d[3] = v.w;
}

// ---------------- embed + LN1, and b0 = amds @ bias_emb ----------------
__global__ __launch_bounds__(64) void embed_kernel(
    const float* __restrict__ nf, const float* __restrict__ amds,
    const float* __restrict__ emb_W, const float* __restrict__ emb_b,
    const float* __restrict__ bemb_W, const float* __restrict__ bemb_b,
    const float* __restrict__ ln1_g, const float* __restrict__ ln1_b,
    float* __restrict__ x, float* __restrict__ b0)
{
    const int n = blockIdx.x;
    const int d = threadIdx.x;
    __shared__ float s_row[kFB];
    #pragma unroll
    for (int r = 0; r < kFB / kD; ++r) s_row[r * kD + d] = nf[n * kFB + r * kD + d];
    __syncthreads();
    float acc = emb_b[d];
    for (int k = 0; k < kFB; ++k) acc = fmaf(s_row[k], emb_W[k * kD + d], acc);
    float mu = acc;
    #pragma unroll
    for (int off = 32; off > 0; off >>= 1) mu += __shfl_xor(mu, off);
    mu *= (1.0f / kD);
    float dv = acc - mu;
    float var = dv * dv;
    #pragma unroll
    for (int off = 32; off > 0; off >>= 1) var += __shfl_xor(var, off);
    var *= (1.0f / kD);
    x[n * kD + d] = dv * rsqrtf(var + kEps) * ln1_g[d] + ln1_b[d];
    __syncthreads();
    s_row[d] = amds[n * kK + d];
    if (d < kK - kD) s_row[kD + d] = amds[n * kK + kD + d];
    __syncthreads();
    float bacc = bemb_b[d];
    for (int k = 0; k < kK; ++k) bacc = fmaf(s_row[k], bemb_W[k * kD + d], bacc);
    b0[n * kD + d] = bacc;
}

// ---------------- bias[i,j,d] = b0[j,d] - b0[i,d] ----------------
__global__ __launch_bounds__(256) void bias_init_kernel(
    const float* __restrict__ b0, float4* __restrict__ bias)
{
    int gid = blockIdx.x * 256 + threadIdx.x;
    int d4 = gid & 15;
    int j  = (gid >> 4) & (kN - 1);
    int i  = gid >> 13;
    const float4* b4 = (const float4*)b0;
    float4 a = b4[j * 16 + d4];
    float4 c = b4[i * 16 + d4];
    bias[gid] = make_float4(a.x - c.x, a.y - c.y, a.z - c.z, a.w - c.w);
}

// ---------------- per-launch weight prep: transpose + bf16 hi/lo split ------
// dWt[l][n][k]  (n<512, k<64)  from diff_W[l][k][n]
// boutWt[l][d][k] (d<64, k<512) from bout_W[l][k][d]
__global__ __launch_bounds__(256) void prep_weights_kernel(
    const float* __restrict__ diff_W, const float* __restrict__ bout_W,
    u16* __restrict__ dWt_hi, u16* __restrict__ dWt_lo,
    u16* __restrict__ boutWt_hi, u16* __restrict__ boutWt_lo)
{
    int gid = blockIdx.x * 256 + threadIdx.x; // 2 * 4 * 32768
    if (gid < 4 * 32768) {
        int e = gid;
        int l = e >> 15;
        int r = e & 32767;
        int k = r >> 9;
        int n = r & 511;
        u16 h, lo;
        bf16_split(diff_W[e], h, lo);
        int w = l * 32768 + n * 64 + k;
        dWt_hi[w] = h; dWt_lo[w] = lo;
    } else {
        int e = gid - 4 * 32768;
        int l = e >> 15;
        int r = e & 32767;
        int k = r >> 6;
        int d = r & 63;
        u16 h, lo;
        bf16_split(bout_W[e], h, lo);
        int w = l * 32768 + d * 512 + k;
        boutWt_hi[w] = h; boutWt_lo[w] = lo;
    }
}

// ---------------- qkv = x @ qkv_W[l] + qkv_b[l] ----------------
__global__ __launch_bounds__(256) void qkv_kernel(
    const float* __restrict__ x, const float* __restrict__ W,
    const float* __restrict__ b, float* __restrict__ qkv)
{
    const int n = blockIdx.y;
    const int c = blockIdx.x * 256 + threadIdx.x;
    __shared__ float s_x[kD];
    if (threadIdx.x < kD) s_x[threadIdx.x] = x[n * kD + threadIdx.x];
    __syncthreads();
    float acc = b[c];
    #pragma unroll 8
    for (int d = 0; d < kD; ++d) acc = fmaf(s_x[d], W[d * (3 * kHHD) + c], acc);
    qkv[n * (3 * kHHD) + c] = acc;
}

// ---------------- fused pair-bias chain, MFMA bf16x3, v3 ----------------
// Block = 64 pairs, 4 waves; wave w owns output col-strip [16w,16w+16).
// Bias A-frags live in VGPRs the whole K-loop. be chunk double-buffered in
// LDS (hi/lo planes interleaved per 8-col group). 1 barrier per chunk.
__global__ __launch_bounds__(256, 3) void bias_layer_mfma(
    float* __restrict__ bias,
    const u16* __restrict__ dWt_hi, const u16* __restrict__ dWt_lo,
    const u16* __restrict__ boutWt_hi, const u16* __restrict__ boutWt_lo,
    const float* __restrict__ diff_b, const float* __restrict__ bout_b,
    float* __restrict__ diffs)
{
    // be layout (u16): idx = buf*8704 + row*136 + (col>>3)*16 + plane*8 + (col&7)
    __shared__ u16 s_be[2 * 64 * 136]; // 34816 B
    __shared__ float s_dp[64 * 4];     // [row][head]

    const int t    = threadIdx.x;
    const int w    = t >> 6;
    const int lane = t & 63;
    const int q    = lane >> 4;
    const int c    = lane & 15;
    const int p0   = blockIdx.x * 64;
    const int i    = p0 >> 9;
    const int j0   = p0 & (kN - 1);

    s_dp[t] = 0.0f;

    // ---- prologue: bias A-frags straight from global, split to bf16 planes
    bf16x8 Ah[4][2], Al[4][2];
    #pragma unroll
    for (int mt = 0; mt < 4; ++mt) {
        #pragma unroll
        for (int s = 0; s < 2; ++s) {
            const float* src = bias + (long)(p0 + mt * 16 + c) * kD + s * 32 + q * 8;
            float4 f0 = *(const float4*)src;
            float4 f1 = *(const float4*)(src + 4);
            u32 h0, l0, h1, l1, h2, l2, h3, l3;
            split2(f0.x, f0.y, h0, l0);
            split2(f0.z, f0.w, h1, l1);
            split2(f1.x, f1.y, h2, l2);
            split2(f1.z, f1.w, h3, l3);
            Ah[mt][s] = mk8(h0, h1, h2, h3);
            Al[mt][s] = mk8(l0, l1, l2, l3);
        }
    }

    // diff_b entries for this lane's column, all 8 chunks
    float dbv[8];
    #pragma unroll
    for (int ch = 0; ch < 8; ++ch) dbv[ch] = diff_b[ch * 64 + w * 16 + c];
    const float bb = bout_b[w * 16 + c];

    f32x4 acc2[4];
    #pragma unroll
    for (int mt = 0; mt < 4; ++mt) acc2[mt] = (f32x4)0.0f;
    float psum[16];
    #pragma unroll
    for (int k = 0; k < 16; ++k) psum[k] = 0.0f;

    const int colg  = (w * 16 + c) >> 3; // be col group
    const int cin   = c & 7;             // within group
    const u16* dWh_base = dWt_hi + (w * 16 + c) * 64 + q * 8;
    const u16* dWl_base = dWt_lo + (w * 16 + c) * 64 + q * 8;
    const u16* oWh_base = boutWt_hi + (w * 16 + c) * 512 + q * 8;
    const u16* oWl_base = boutWt_lo + (w * 16 + c) * 512 + q * 8;

    for (int ch = 0; ch < 8; ++ch) {
        // ---- GEMM1: acc1 = bias_tile @ dW chunk (A in regs, B from global/L1)
        const u16* dh = dWh_base + ch * 64 * 64;
        const u16* dl = dWl_base + ch * 64 * 64;
        bf16x8 b1h0 = *(const bf16x8*)dh;
        bf16x8 b1h1 = *(const bf16x8*)(dh + 32);
        bf16x8 b1l0 = *(const bf16x8*)dl;
        bf16x8 b1l1 = *(const bf16x8*)(dl + 32);

        f32x4 acc1[4];
        #pragma unroll
        for (int mt = 0; mt < 4; ++mt) acc1[mt] = (f32x4)0.0f;
        #pragma unroll
        for (int mt = 0; mt < 4; ++mt) {
            acc1[mt] = __builtin_amdgcn_mfma_f32_16x16x32_bf16(Ah[mt][0], b1h0, acc1[mt], 0, 0, 0);
            acc1[mt] = __builtin_amdgcn_mfma_f32_16x16x32_bf16(Al[mt][0], b1h0, acc1[mt], 0, 0, 0);
            acc1[mt] = __builtin_amdgcn_mfma_f32_16x16x32_bf16(Ah[mt][0], b1l0, acc1[mt], 0, 0, 0);
            acc1[mt] = __builtin_amdgcn_mfma_f32_16x16x32_bf16(Ah[mt][1], b1h1, acc1[mt], 0, 0, 0);
            acc1[mt] = __builtin_amdgcn_mfma_f32_16x16x32_bf16(Al[mt][1], b1h1, acc1[mt], 0, 0, 0);
            acc1[mt] = __builtin_amdgcn_mfma_f32_16x16x32_bf16(Ah[mt][1], b1l1, acc1[mt], 0, 0, 0);
        }

        // ---- mish + psum + split -> be planes (this wave's col-strip)
        const float dbc = dbv[ch];
        u16* beW = s_be + (ch & 1) * 8704 + colg * 16 + cin;
        #pragma unroll
        for (int mt = 0; mt < 4; ++mt) {
            float v0 = mish_f(acc1[mt][0] + dbc);
            float v1 = mish_f(acc1[mt][1] + dbc);
            float v2 = mish_f(acc1[mt][2] + dbc);
            float v3 = mish_f(acc1[mt][3] + dbc);
            psum[mt * 4 + 0] += v0 * v0;
            psum[mt * 4 + 1] += v1 * v1;
            psum[mt * 4 + 2] += v2 * v2;
            psum[mt * 4 + 3] += v3 * v3;
            u32 h01, l01, h23, l23;
            split2(v0, v1, h01, l01);
            split2(v2, v3, h23, l23);
            int r0 = (mt * 16 + 4 * q) * 136;
            beW[r0]             = (u16)h01;
            beW[r0 + 136]       = (u16)(h01 >> 16);
            beW[r0 + 272]       = (u16)h23;
            beW[r0 + 408]       = (u16)(h23 >> 16);
            beW[r0 + 8]         = (u16)l01;
            beW[r0 + 136 + 8]   = (u16)(l01 >> 16);
            beW[r0 + 272 + 8]   = (u16)l23;
            beW[r0 + 408 + 8]   = (u16)(l23 >> 16);
        }

        // ---- per-head psum flush (every 2 chunks)
        if (ch & 1) {
            #pragma unroll
            for (int k = 0; k < 16; ++k) {
                psum[k] += __shfl_xor(psum[k], 1);
                psum[k] += __shfl_xor(psum[k], 2);
                psum[k] += __shfl_xor(psum[k], 4);
                psum[k] += __shfl_xor(psum[k], 8);
            }
            if (c == 0) {
                int h = ch >> 1;
                #pragma unroll
                for (int mt = 0; mt < 4; ++mt)
                    #pragma unroll
                    for (int r = 0; r < 4; ++r)
                        atomicAdd(&s_dp[(mt * 16 + 4 * q + r) * 4 + h], psum[mt * 4 + r]);
            }
            #pragma unroll
            for (int k = 0; k < 16; ++k) psum[k] = 0.0f;
        }

        __syncthreads(); // be chunk complete (all col-strips)

        // ---- GEMM2: acc2 += be_chunk @ bout_W chunk
        const u16* oh = oWh_base + ch * 64;
        const u16* ol = oWl_base + ch * 64;
        bf16x8 b2h0 = *(const bf16x8*)oh;
        bf16x8 b2h1 = *(const bf16x8*)(oh + 32);
        bf16x8 b2l0 = *(const bf16x8*)ol;
        bf16x8 b2l1 = *(const bf16x8*)(ol + 32);
        const u16* beR = s_be + (ch & 1) * 8704;
        #pragma unroll
        for (int mt = 0; mt < 4; ++mt) {
            const u16* rowp = beR + (mt * 16 + c) * 136;
            bf16x8 eh0 = *(const bf16x8*)(rowp + q * 16);
            bf16x8 el0 = *(const bf16x8*)(rowp + q * 16 + 8);
            bf16x8 eh1 = *(const bf16x8*)(rowp + (4 + q) * 16);
            bf16x8 el1 = *(const bf16x8*)(rowp + (4 + q) * 16 + 8);
            acc2[mt] = __builtin_amdgcn_mfma_f32_16x16x32_bf16(eh0, b2h0, acc2[mt], 0, 0, 0);
            acc2[mt] = __builtin_amdgcn_mfma_f32_16x16x32_bf16(el0, b2h0, acc2[mt], 0, 0, 0);
            acc2[mt] = __builtin_amdgcn_mfma_f32_16x16x32_bf16(eh0, b2l0, acc2[mt], 0, 0, 0);
            acc2[mt] = __builtin_amdgcn_mfma_f32_16x16x32_bf16(eh1, b2h1, acc2[mt], 0, 0, 0);
            acc2[mt] = __builtin_amdgcn_mfma_f32_16x16x32_bf16(el1, b2h1, acc2[mt], 0, 0, 0);
            acc2[mt] = __builtin_amdgcn_mfma_f32_16x16x32_bf16(eh1, b2l1, acc2[mt], 0, 0, 0);
        }
    }

    // ---- epilogue: bias tile in place + diffs
    #pragma unroll
    for (int mt = 0; mt < 4; ++mt) {
        #pragma unroll
        for (int r = 0; r < 4; ++r) {
            float v = mish_f(acc2[mt][r] + bb);
            bias[(long)(p0 + mt * 16 + 4 * q + r) * kD + w * 16 + c] = v;
        }
    }
    {
        int row = t >> 2;
        int h2  = t & 3;
        diffs[h2 * (kN * kN) + i * kN + (j0 + row)] = sqrtf(s_dp[row * 4 + h2]);
    }
}

// ---------------- logits[h,n,m] = scale*q.k + diffs ----------------
__global__ __launch_bounds__(256) void logits_kernel(
    const float* __restrict__ qkv, const float* __restrict__ diffs,
    float* __restrict__ logits)
{
    constexpr int SW = 68;
    __shared__ float s_q[64 * SW];
    __shared__ float s_k[64 * SW];
    const int t  = threadIdx.x;
    const int tX = t & 15;
    const int tY = t >> 4;
    const int h  = blockIdx.z;
    const int n0 = blockIdx.x * 64;
    const int m0 = blockIdx.y * 64;

    float acc[4][4];
    #pragma unroll
    for (int a = 0; a < 4; ++a)
        #pragma unroll
        for (int b = 0; b < 4; ++b) acc[a][b] = 0.0f;

    for (int dc = 0; dc < 2; ++dc) {
        __syncthreads();
        #pragma unroll
        for (int rep = 0; rep < 4; ++rep) {
            int f = rep * 256 + t;
            int row = f >> 4;
            int c4  = f & 15;
            *(float4*)&s_q[row * SW + c4 * 4] =
                *(const float4*)&qkv[(n0 + row) * (3 * kHHD) + h * 384 + dc * 64 + c4 * 4];
            *(float4*)&s_k[row * SW + c4 * 4] =
                *(const float4*)&qkv[(m0 + row) * (3 * kHHD) + h * 384 + 128 + dc * 64 + c4 * 4];
        }
        __syncthreads();
        for (int d = 0; d < 64; d += 4) {
            float a[4][4], b[4][4];
            #pragma unroll
            for (int rr = 0; rr < 4; ++rr) ld4(a[rr], &s_q[(tY + 16 * rr) * SW + d]);
            #pragma unroll
            for (int cc = 0; cc < 4; ++cc) ld4(b[cc], &s_k[(tX + 16 * cc) * SW + d]);
            #pragma unroll
            for (int rr = 0; rr < 4; ++rr)
                #pragma unroll
                for (int cc = 0; cc < 4; ++cc)
                    #pragma unroll
                    for (int u = 0; u < 4; ++u)
                        acc[rr][cc] = fmaf(a[rr][u], b[cc][u], acc[rr][cc]);
        }
    }
    #pragma unroll
    for (int rr = 0; rr < 4; ++rr)
        #pragma unroll
        for (int cc = 0; cc < 4; ++cc) {
            int row = n0 + tY + 16 * rr;
            int col = m0 + tX + 16 * cc;
            long idx = (long)h * (kN * kN) + (long)row * kN + col;
            logits[idx] = acc[rr][cc] * kScale + diffs[idx];
        }
}

// ---------------- softmax over m, per (h,n) row ----------------
__global__ __launch_bounds__(256) void softmax_kernel(float* __restrict__ logits)
{
    const int row = blockIdx.x;
    float* p = logits + (long)row * kN;
    const int t = threadIdx.x;
    float v0 = p[t];
    float v1 = p[t + 256];
    float m = fmaxf(v0, v1);
    #pragma unroll
    for (int off = 32; off > 0; off >>= 1) m = fmaxf(m, __shfl_xor(m, off));
    __shared__ float s_red[4];
    __shared__ float s_sum[4];
    if ((t & 63) == 0) s_red[t >> 6] = m;
    __syncthreads();
    m = fmaxf(fmaxf(s_red[0], s_red[1]), fmaxf(s_red[2], s_red[3]));
    float e0 = expf(v0 - m);
    float e1 = expf(v1 - m);
    float s = e0 + e1;
    #pragma unroll
    for (int off = 32; off > 0; off >>= 1) s += __shfl_xor(s, off);
    if ((t & 63) == 0) s_sum[t >> 6] = s;
    __syncthreads();
    s = (s_sum[0] + s_sum[1]) + (s_sum[2] + s_sum[3]);
    float inv = 1.0f / s;
    p[t] = e0 * inv;
    p[t + 256] = e1 * inv;
}

// ---------------- vals[n, h*128+d] = sum_m attn[h,n,m]*v[m,h,d] ----------------
__global__ __launch_bounds__(256) void attnv_kernel(
    const float* __restrict__ attn, const float* __restrict__ qkv,
    float* __restrict__ vals)
{
    constexpr int SW = 68;
    __shared__ float s_p[64 * SW];
    __shared__ float s_v[64 * SW];
    const int t  = threadIdx.x;
    const int tx = t & 15;
    const int ty = t >> 4;
    const int h  = blockIdx.z;
    const int n0 = blockIdx.x * 64;
    const int d0 = blockIdx.y * 64;

    float acc[4][4];
    #pragma unroll
    for (int a = 0; a < 4; ++a)
        #pragma unroll
        for (int b = 0; b < 4; ++b) acc[a][b] = 0.0f;

    for (int mt = 0; mt < 8; ++mt) {
        const int m0 = mt * 64;
        __syncthreads();
        #pragma unroll
        for (int rep = 0; rep < 4; ++rep) {
            int f = rep * 256 + t;
            int row = f >> 4;
            int c4  = f & 15;
            *(float4*)&s_p[row * SW + c4 * 4] =
                *(const float4*)&attn[(long)h * (kN * kN) + (long)(n0 + row) * kN + m0 + c4 * 4];
            *(float4*)&s_v[row * SW + c4 * 4] =
                *(const float4*)&qkv[(m0 + row) * (3 * kHHD) + h * 384 + 256 + d0 + c4 * 4];
        }
        __syncthreads();
        for (int kk = 0; kk < 64; kk += 4) {
            float a[4][4], b[4][4];
            #pragma unroll
            for (int rr = 0; rr < 4; ++rr) ld4(a[rr], &s_p[(4 * ty + rr) * SW + kk]);
            #pragma unroll
            for (int u = 0; u < 4; ++u) ld4(b[u], &s_v[(kk + u) * SW + 4 * tx]);
            #pragma unroll
            for (int rr = 0; rr < 4; ++rr)
                #pragma unroll
                for (int cc = 0; cc < 4; ++cc)
                    #pragma unroll
                    for (int u = 0; u < 4; ++u)
                        acc[rr][cc] = fmaf(a[rr][u], b[u][cc], acc[rr][cc]);
        }
    }
    #pragma unroll
    for (int rr = 0; rr < 4; ++rr) {
        float4 o = make_float4(acc[rr][0], acc[rr][1], acc[rr][2], acc[rr][3]);
        *(float4*)&vals[(long)(n0 + 4 * ty + rr) * kHHD + h * kHD + d0 + 4 * tx] = o;
    }
}

// ---------------- x = LN2(x + vals@o_W + o_b) ----------------
__global__ __launch_bounds__(64) void oproj_ln_kernel(
    const float* __restrict__ vals, const float* __restrict__ o_W,
    const float* __restrict__ o_b, const float* __restrict__ g2,
    const float* __restrict__ b2, float* __restrict__ x)
{
    const int n = blockIdx.x;
    const int d = threadIdx.x;
    __shared__ float s_v[kHHD];
    #pragma unroll
    for (int r = 0; r < kHHD / kD; ++r) s_v[r * kD + d] = vals[n * kHHD + r * kD + d];
    __syncthreads();
    float acc = o_b[d];
    for (int j = 0; j < kHHD; ++j) acc = fmaf(s_v[j], o_W[j * kD + d], acc);
    float xv = x[n * kD + d] + acc;
    float mu = xv;
    #pragma unroll
    for (int off = 32; off > 0; off >>= 1) mu += __shfl_xor(mu, off);
    mu *= (1.0f / kD);
    float dv = xv - mu;
    float var = dv * dv;
    #pragma unroll
    for (int off = 32; off > 0; off >>= 1) var += __shfl_xor(var, off);
    var *= (1.0f / kD);
    x[n * kD + d] = dv * rsqrtf(var + kEps) * g2[d] + b2[d];
}

// ---------------- out = x @ out_W + out_b ----------------
__global__ __launch_bounds__(64) void final_kernel(
    const float* __restrict__ x, const float* __restrict__ out_W,
    const float* __restrict__ out_b, float* __restrict__ out)
{
    const int n = blockIdx.x * 64 + threadIdx.x;
    float acc = out_b[0];
    #pragma unroll
    for (int d = 0; d < kD; ++d) acc = fmaf(x[n * kD + d], out_W[d], acc);
    out[n] = acc;
}

} // anonymous namespace

extern "C" void kernel_launch(void* const* d_in, const int* in_sizes, int n_in,
                              void* d_out, int out_size, void* d_ws, size_t ws_size,
                              hipStream_t stream)
{
    (void)in_sizes; (void)n_in; (void)out_size; (void)ws_size;

    const float* nf     = (const float*)d_in[0];
    const float* amds   = (const float*)d_in[1];
    const float* emb_W  = (const float*)d_in[2];
    const float* emb_b  = (const float*)d_in[3];
    const float* bemb_W = (const float*)d_in[4];
    const float* bemb_b = (const float*)d_in[5];
    const float* ln1_g  = (const float*)d_in[6];
    const float* ln1_b  = (const float*)d_in[7];
    const float* ln2_g  = (const float*)d_in[8];
    const float* ln2_b  = (const float*)d_in[9];
    const float* qkv_W  = (const float*)d_in[10];
    const float* qkv_b  = (const float*)d_in[11];
    const float* diff_W = (const float*)d_in[12];
    const float* diff_b = (const float*)d_in[13];
    const float* o_W    = (const float*)d_in[14];
    const float* o_b    = (const float*)d_in[15];
    const float* bout_W = (const float*)d_in[16];
    const float* bout_b = (const float*)d_in[17];
    const float* out_W  = (const float*)d_in[18];
    const float* out_b  = (const float*)d_in[19];

    float* ws = (float*)d_ws;
    float* ws_x      = ws;                   // 512*64
    float* ws_b0     = ws_x + 32768;         // 512*64
    float* ws_qkv    = ws_b0 + 32768;        // 512*1536
    float* ws_vals   = ws_qkv + 786432;      // 512*512
    float* ws_diffs  = ws_vals + 262144;     // 4*512*512
    float* ws_logits = ws_diffs + 1048576;   // 4*512*512
    float* ws_bias   = ws_logits + 1048576;  // 512*512*64
    u16*   ws_u      = (u16*)(ws_bias + 16777216);
    u16* dWt_hi    = ws_u;                   // 4*512*64
    u16* dWt_lo    = dWt_hi + 131072;
    u16* boutWt_hi = dWt_lo + 131072;        // 4*64*512
    u16* boutWt_lo = boutWt_hi + 131072;

    embed_kernel<<<kN, kD, 0, stream>>>(nf, amds, emb_W, emb_b, bemb_W, bemb_b,
                                        ln1_g, ln1_b, ws_x, ws_b0);
    bias_init_kernel<<<(kN * kN * kD / 4) / 256, 256, 0, stream>>>(
        ws_b0, (float4*)ws_bias);
    prep_weights_kernel<<<(2 * 4 * 32768) / 256, 256, 0, stream>>>(
        diff_W, bout_W, dWt_hi, dWt_lo, boutWt_hi, boutWt_lo);

    for (int l = 0; l < 4; ++l) {
        qkv_kernel<<<dim3(6, kN), 256, 0, stream>>>(
            ws_x, qkv_W + l * kD * (3 * kHHD), qkv_b + l * (3 * kHHD), ws_qkv);
        bias_layer_mfma<<<kN * kN / 64, 256, 0, stream>>>(
            ws_bias, dWt_hi + l * 32768, dWt_lo + l * 32768,
            boutWt_hi + l * 32768, boutWt_lo + l * 32768,
            diff_b + l * kHHD, bout_b + l * kD, ws_diffs);
        logits_kernel<<<dim3(8, 8, kH), 256, 0, stream>>>(ws_qkv, ws_diffs, ws_logits);
        softmax_kernel<<<kH * kN, 256, 0, stream>>>(ws_logits);
        attnv_kernel<<<dim3(8, 2, kH), 256, 0, stream>>>(ws_logits, ws_qkv, ws_vals);
        oproj_ln_kernel<<<kN, kD, 0, stream>>>(
            ws_vals, o_W + l * kHHD * kD, o_b + l * kD, ln2_g, ln2_b, ws_x);
    }
    final_kernel<<<kN / kD, kD, 0, stream>>>(ws_x, out_W, out_b, (float*)d_out);
}

// Round 4
// 924.973 us; speedup vs baseline: 4.2057x; 1.2891x over previous
//
#include <hip/hip_runtime.h>
#include <hip/hip_bf16.h>
#include <cmath>

// CrAKN fused implementation.
// R4: bias chain restructured so GEMM1 computes be^T with a row-permuted A
// operand (W1^T); the MFMA C-layout of GEMM1 then coincides exactly with the
// A-fragment layout GEMM2 needs -> no LDS round-trip, no barrier, no shuffle
// between the two GEMMs. Each wave owns 32 pairs end-to-end; LDS only stages
// weights (XOR-swizzled, double-buffered) shared by the block's 4 waves.

namespace {

constexpr int kN   = 512;
constexpr int kD   = 64;
constexpr int kH   = 4;
constexpr int kHD  = 128;
constexpr int kHHD = 512;
constexpr int kFB  = 256;
constexpr int kK   = 100;
constexpr float kEps   = 1e-5f;
constexpr float kScale = 0.08838834764831845f; // 1/sqrt(128)

typedef unsigned short u16;
typedef unsigned int u32;
typedef short bf16x8 __attribute__((ext_vector_type(8)));
typedef float f32x4 __attribute__((ext_vector_type(4)));

// mish(x) = x*tanh(softplus(x)) = x * n/(n+2), n = e*(e+2), e = exp(x).
__device__ __forceinline__ float mish_f(float x) {
    float e = __expf(fminf(x, 15.0f));
    float n = e * (e + 2.0f);
    return x * n * __builtin_amdgcn_rcpf(n + 2.0f);
}

__device__ __forceinline__ u32 pk_bf16(float a, float b) {
    union { __hip_bfloat162 v; u32 u; } cv;
    cv.v = __float22bfloat162_rn(make_float2(a, b));
    return cv.u; // a low 16, b high 16
}
__device__ __forceinline__ void split2(float a, float b, u32& hi, u32& lo) {
    hi = pk_bf16(a, b);
    float fa = __uint_as_float(hi << 16);
    float fb = __uint_as_float(hi & 0xFFFF0000u);
    lo = pk_bf16(a - fa, b - fb);
}
__device__ __forceinline__ bf16x8 mk8(u32 a, u32 b, u32 c, u32 d) {
    union { u32 w[4]; bf16x8 v; } cv;
    cv.w[0] = a; cv.w[1] = b; cv.w[2] = c; cv.w[3] = d;
    return cv.v;
}

__device__ __forceinline__ u16 bf16_rne(float f) {
    u32 u = __float_as_uint(f);
    u = u + 0x7FFFu + ((u >> 16) & 1u);
    return (u16)(u >> 16);
}
__device__ __forceinline__ void bf16_split(float f, u16& h, u16& l) {
    h = bf16_rne(f);
    float fh = __uint_as_float((u32)h << 16);
    l = bf16_rne(f - fh);
}

__device__ __forceinline__ void ld4(float* d, const float* s) {
    float4 v = *(const float4*)s;
    d[0] = v.x; d[1] = v.y; d[2] = v.z; d[3] = v.w;
}

// ---------------- embed + LN1, and b0 = amds @ bias_emb ----------------
__global__ __launch_bounds__(64) void embed_kernel(
    const float* __restrict__ nf, const float* __restrict__ amds,
    const float* __restrict__ emb_W, const float* __restrict__ emb_b,
    const float* __restrict__ bemb_W, const float* __restrict__ bemb_b,
    const float* __restrict__ ln1_g, const float* __restrict__ ln1_b,
    float* __restrict__ x, float* __restrict__ b0)
{
    const int n = blockIdx.x;
    const int d = threadIdx.x;
    __shared__ float s_row[kFB];
    #pragma unroll
    for (int r = 0; r < kFB / kD; ++r) s_row[r * kD + d] = nf[n * kFB + r * kD + d];
    __syncthreads();
    float acc = emb_b[d];
    for (int k = 0; k < kFB; ++k) acc = fmaf(s_row[k], emb_W[k * kD + d], acc);
    float mu = acc;
    #pragma unroll
    for (int off = 32; off > 0; off >>= 1) mu += __shfl_xor(mu, off);
    mu *= (1.0f / kD);
    float dv = acc - mu;
    float var = dv * dv;
    #pragma unroll
    for (int off = 32; off > 0; off >>= 1) var += __shfl_xor(var, off);
    var *= (1.0f / kD);
    x[n * kD + d] = dv * rsqrtf(var + kEps) * ln1_g[d] + ln1_b[d];
    __syncthreads();
    s_row[d] = amds[n * kK + d];
    if (d < kK - kD) s_row[kD + d] = amds[n * kK + kD + d];
    __syncthreads();
    float bacc = bemb_b[d];
    for (int k = 0; k < kK; ++k) bacc = fmaf(s_row[k], bemb_W[k * kD + d], bacc);
    b0[n * kD + d] = bacc;
}

// ---------------- bias[i,j,d] = b0[j,d] - b0[i,d] ----------------
__global__ __launch_bounds__(256) void bias_init_kernel(
    const float* __restrict__ b0, float4* __restrict__ bias)
{
    int gid = blockIdx.x * 256 + threadIdx.x;
    int d4 = gid & 15;
    int j  = (gid >> 4) & (kN - 1);
    int i  = gid >> 13;
    const float4* b4 = (const float4*)b0;
    float4 a = b4[j * 16 + d4];
    float4 c = b4[i * 16 + d4];
    bias[gid] = make_float4(a.x - c.x, a.y - c.y, a.z - c.z, a.w - c.w);
}

// ---------------- per-launch weight prep: transpose + bf16 hi/lo split ------
// dWt[l][n][k]  (n<512, k<64)  from diff_W[l][k][n]
// boutWt[l][d][k] (d<64, k<512) from bout_W[l][k][d]
__global__ __launch_bounds__(256) void prep_weights_kernel(
    const float* __restrict__ diff_W, const float* __restrict__ bout_W,
    u16* __restrict__ dWt_hi, u16* __restrict__ dWt_lo,
    u16* __restrict__ boutWt_hi, u16* __restrict__ boutWt_lo)
{
    int gid = blockIdx.x * 256 + threadIdx.x; // 2 * 4 * 32768
    if (gid < 4 * 32768) {
        int e = gid;
        int l = e >> 15;
        int r = e & 32767;
        int k = r >> 9;
        int n = r & 511;
        u16 h, lo;
        bf16_split(diff_W[e], h, lo);
        int w = l * 32768 + n * 64 + k;
        dWt_hi[w] = h; dWt_lo[w] = lo;
    } else {
        int e = gid - 4 * 32768;
        int l = e >> 15;
        int r = e & 32767;
        int k = r >> 6;
        int d = r & 63;
        u16 h, lo;
        bf16_split(bout_W[e], h, lo);
        int w = l * 32768 + d * 512 + k;
        boutWt_hi[w] = h; boutWt_lo[w] = lo;
    }
}

// ---------------- qkv = x @ qkv_W[l] + qkv_b[l] ----------------
__global__ __launch_bounds__(256) void qkv_kernel(
    const float* __restrict__ x, const float* __restrict__ W,
    const float* __restrict__ b, float* __restrict__ qkv)
{
    const int n = blockIdx.y;
    const int c = blockIdx.x * 256 + threadIdx.x;
    __shared__ float s_x[kD];
    if (threadIdx.x < kD) s_x[threadIdx.x] = x[n * kD + threadIdx.x];
    __syncthreads();
    float acc = b[c];
    #pragma unroll 8
    for (int d = 0; d < kD; ++d) acc = fmaf(s_x[d], W[d * (3 * kHHD) + c], acc);
    qkv[n * (3 * kHHD) + c] = acc;
}

// ---------------- fused pair-bias chain, MFMA bf16x3, v4 ----------------
// Block = 128 pairs (4 waves x 32). Per 32-becol group-pair g2:
//   GEMM1 (be^T): A = W1^T rows permuted so that the C output at lane (q,c),
//   tile u, reg r holds be[pair=c][bc = 32*g2 + 8q + 4u + r] -- which is
//   exactly the A-fragment element k=quad*8+j (j=4u+r) for GEMM2 (16x16x32).
//   GEMM2: acc2 += be_chunk @ W2 chunk. No inter-GEMM LDS/permute needed.
// LDS stages W1/W2 chunks (XOR-swizzled, double-buffered), 1 barrier/g2.
__global__ __launch_bounds__(256, 3) void bias_layer_mfma(
    float* __restrict__ bias,
    const u16* __restrict__ dWt_hi, const u16* __restrict__ dWt_lo,
    const u16* __restrict__ boutWt_hi, const u16* __restrict__ boutWt_lo,
    const float* __restrict__ diff_b, const float* __restrict__ bout_b,
    float* __restrict__ diffs)
{
    // [buf][plane][ w1: 32 rows * 64 u16 | w2 at 2048: 64 rows * 32 u16 ]
    __shared__ u16 s_w[2][2][4096]; // 32 KB

    const int t    = threadIdx.x;
    const int w    = t >> 6;
    const int lane = t & 63;
    const int q    = lane >> 4;
    const int c    = lane & 15;
    const int pb   = blockIdx.x * 128 + w * 32;  // wave's 32 pairs

    // --- staging indices (per thread): W1 row-permuted + k-block XOR swizzle
    const int sb_bc  = t >> 3;       // source W1^T row within chunk (0..31)
    const int sb_kb  = t & 7;        // k block (8 u16 each)
    const int sr     = ((sb_bc >> 2) & 1) * 16 + ((sb_bc >> 3) << 2) + (sb_bc & 3);
    const int w1_dst = sr * 64 + (sb_kb ^ (sr & 7)) * 8;
    const int sb_d   = t >> 2;       // W2 row d (0..63)
    const int sb_k2  = t & 3;        // k block within 32
    const int w2_dst = 2048 + sb_d * 32 + (sb_k2 ^ ((sb_d >> 1) & 3)) * 8;
    const u16* g_w1h = dWt_hi + sb_bc * 64 + sb_kb * 8;
    const u16* g_w1l = dWt_lo + sb_bc * 64 + sb_kb * 8;
    const u16* g_w2h = boutWt_hi + sb_d * 512 + sb_k2 * 8;
    const u16* g_w2l = boutWt_lo + sb_d * 512 + sb_k2 * 8;

    // --- B-frags: bias^T for two 16-pair tiles, K=64 (kept in regs all loop)
    bf16x8 Bh[2][2], Bl[2][2];
    #pragma unroll
    for (int mt = 0; mt < 2; ++mt) {
        #pragma unroll
        for (int s = 0; s < 2; ++s) {
            const float* src = bias + (long)(pb + mt * 16 + c) * kD + s * 32 + q * 8;
            float4 f0 = *(const float4*)src;
            float4 f1 = *(const float4*)(src + 4);
            u32 h0, l0, h1, l1, h2, l2, h3, l3;
            split2(f0.x, f0.y, h0, l0);
            split2(f0.z, f0.w, h1, l1);
            split2(f1.x, f1.y, h2, l2);
            split2(f1.z, f1.w, h3, l3);
            Bh[mt][s] = mk8(h0, h1, h2, h3);
            Bl[mt][s] = mk8(l0, l1, l2, l3);
        }
    }

    // --- prologue stage g2=0 into buf 0
    {
        bf16x8 r0 = *(const bf16x8*)g_w1h;
        bf16x8 r1 = *(const bf16x8*)g_w1l;
        bf16x8 r2 = *(const bf16x8*)g_w2h;
        bf16x8 r3 = *(const bf16x8*)g_w2l;
        *(bf16x8*)&s_w[0][0][w1_dst] = r0;
        *(bf16x8*)&s_w[0][1][w1_dst] = r1;
        *(bf16x8*)&s_w[0][0][w2_dst] = r2;
        *(bf16x8*)&s_w[0][1][w2_dst] = r3;
    }
    __syncthreads();

    f32x4 acc2[2][4];
    #pragma unroll
    for (int mt = 0; mt < 2; ++mt)
        #pragma unroll
        for (int dg = 0; dg < 4; ++dg) acc2[mt][dg] = (f32x4)0.0f;
    float psum[2][4];
    #pragma unroll
    for (int mt = 0; mt < 2; ++mt)
        #pragma unroll
        for (int h = 0; h < 4; ++h) psum[mt][h] = 0.0f;

    const int sw1 = c & 7;          // W1 read swizzle key
    const int sw2 = (c >> 1) & 3;   // W2 read swizzle key
    int cur = 0;

    for (int g2 = 0; g2 < 16; ++g2) {
        // prefetch next weight chunk into regs (consumed after compute)
        bf16x8 r0, r1, r2, r3;
        if (g2 < 15) {
            r0 = *(const bf16x8*)(g_w1h + (g2 + 1) * 2048);
            r1 = *(const bf16x8*)(g_w1l + (g2 + 1) * 2048);
            r2 = *(const bf16x8*)(g_w2h + (g2 + 1) * 32);
            r3 = *(const bf16x8*)(g_w2l + (g2 + 1) * 32);
        }

        // ---- GEMM1: a1[mt][u] = W1^T(permuted rows) x bias^T
        f32x4 a1[2][2];
        #pragma unroll
        for (int mt = 0; mt < 2; ++mt)
            #pragma unroll
            for (int u = 0; u < 2; ++u) a1[mt][u] = (f32x4)0.0f;
        const u16* w1h = &s_w[cur][0][0];
        const u16* w1l = &s_w[cur][1][0];
        #pragma unroll
        for (int u = 0; u < 2; ++u) {
            int row = (u * 16 + c) * 64;
            int o0 = row + ((0 + q) ^ sw1) * 8; // s=0
            int o1 = row + ((4 + q) ^ sw1) * 8; // s=1
            bf16x8 A0h = *(const bf16x8*)(w1h + o0);
            bf16x8 A1h = *(const bf16x8*)(w1h + o1);
            bf16x8 A0l = *(const bf16x8*)(w1l + o0);
            bf16x8 A1l = *(const bf16x8*)(w1l + o1);
            #pragma unroll
            for (int mt = 0; mt < 2; ++mt) {
                a1[mt][u] = __builtin_amdgcn_mfma_f32_16x16x32_bf16(A0h, Bh[mt][0], a1[mt][u], 0, 0, 0);
                a1[mt][u] = __builtin_amdgcn_mfma_f32_16x16x32_bf16(A0l, Bh[mt][0], a1[mt][u], 0, 0, 0);
                a1[mt][u] = __builtin_amdgcn_mfma_f32_16x16x32_bf16(A0h, Bl[mt][0], a1[mt][u], 0, 0, 0);
                a1[mt][u] = __builtin_amdgcn_mfma_f32_16x16x32_bf16(A1h, Bh[mt][1], a1[mt][u], 0, 0, 0);
                a1[mt][u] = __builtin_amdgcn_mfma_f32_16x16x32_bf16(A1l, Bh[mt][1], a1[mt][u], 0, 0, 0);
                a1[mt][u] = __builtin_amdgcn_mfma_f32_16x16x32_bf16(A1h, Bl[mt][1], a1[mt][u], 0, 0, 0);
            }
        }

        // ---- mish + psum + split; C-layout IS GEMM2 A-layout (j = 4u+r)
        const int hd = g2 >> 2;
        bf16x8 Ah[2], Al[2];
        #pragma unroll
        for (int mt = 0; mt < 2; ++mt) {
            u32 hh[2][2], lv[2][2];
            #pragma unroll
            for (int u = 0; u < 2; ++u) {
                float4 db = *(const float4*)(diff_b + g2 * 32 + q * 8 + u * 4);
                float v0 = mish_f(a1[mt][u][0] + db.x);
                float v1 = mish_f(a1[mt][u][1] + db.y);
                float v2 = mish_f(a1[mt][u][2] + db.z);
                float v3 = mish_f(a1[mt][u][3] + db.w);
                psum[mt][hd] += v0 * v0 + v1 * v1 + v2 * v2 + v3 * v3;
                split2(v0, v1, hh[u][0], lv[u][0]);
                split2(v2, v3, hh[u][1], lv[u][1]);
            }
            Ah[mt] = mk8(hh[0][0], hh[0][1], hh[1][0], hh[1][1]);
            Al[mt] = mk8(lv[0][0], lv[0][1], lv[1][0], lv[1][1]);
        }

        // ---- GEMM2: acc2 += be_chunk @ W2 chunk
        const u16* w2h = &s_w[cur][0][2048];
        const u16* w2l = &s_w[cur][1][2048];
        const int kb2 = (q ^ sw2) * 8;
        #pragma unroll
        for (int dg = 0; dg < 4; ++dg) {
            int bo = dg * 512 + c * 32 + kb2;
            bf16x8 Wh = *(const bf16x8*)(w2h + bo);
            bf16x8 Wl = *(const bf16x8*)(w2l + bo);
            #pragma unroll
            for (int mt = 0; mt < 2; ++mt) {
                acc2[mt][dg] = __builtin_amdgcn_mfma_f32_16x16x32_bf16(Ah[mt], Wh, acc2[mt][dg], 0, 0, 0);
                acc2[mt][dg] = __builtin_amdgcn_mfma_f32_16x16x32_bf16(Al[mt], Wh, acc2[mt][dg], 0, 0, 0);
                acc2[mt][dg] = __builtin_amdgcn_mfma_f32_16x16x32_bf16(Ah[mt], Wl, acc2[mt][dg], 0, 0, 0);
            }
        }

        // ---- commit prefetched chunk, flip buffers
        if (g2 < 15) {
            int nb = cur ^ 1;
            *(bf16x8*)&s_w[nb][0][w1_dst] = r0;
            *(bf16x8*)&s_w[nb][1][w1_dst] = r1;
            *(bf16x8*)&s_w[nb][0][w2_dst] = r2;
            *(bf16x8*)&s_w[nb][1][w2_dst] = r3;
            __syncthreads();
            cur = nb;
        }
    }

    // ---- epilogue: bias tile in place + diffs
    #pragma unroll
    for (int mt = 0; mt < 2; ++mt) {
        #pragma unroll
        for (int dg = 0; dg < 4; ++dg) {
            float bb = bout_b[dg * 16 + c];
            #pragma unroll
            for (int r = 0; r < 4; ++r) {
                float v = mish_f(acc2[mt][dg][r] + bb);
                bias[(long)(pb + mt * 16 + 4 * q + r) * kD + dg * 16 + c] = v;
            }
        }
    }
    const int i  = blockIdx.x >> 2;
    const int jb = (blockIdx.x & 3) * 128 + w * 32;
    #pragma unroll
    for (int mt = 0; mt < 2; ++mt) {
        #pragma unroll
        for (int h = 0; h < 4; ++h) {
            psum[mt][h] += __shfl_xor(psum[mt][h], 16);
            psum[mt][h] += __shfl_xor(psum[mt][h], 32);
        }
        float sv = (q == 0) ? psum[mt][0] : (q == 1) ? psum[mt][1]
                 : (q == 2) ? psum[mt][2] : psum[mt][3];
        diffs[q * (kN * kN) + i * kN + jb + mt * 16 + c] = sqrtf(sv);
    }
}

// ---------------- logits[h,n,m] = scale*q.k + diffs ----------------
__global__ __launch_bounds__(256) void logits_kernel(
    const float* __restrict__ qkv, const float* __restrict__ diffs,
    float* __restrict__ logits)
{
    constexpr int SW = 68;
    __shared__ float s_q[64 * SW];
    __shared__ float s_k[64 * SW];
    const int t  = threadIdx.x;
    const int tX = t & 15;
    const int tY = t >> 4;
    const int h  = blockIdx.z;
    const int n0 = blockIdx.x * 64;
    const int m0 = blockIdx.y * 64;

    float acc[4][4];
    #pragma unroll
    for (int a = 0; a < 4; ++a)
        #pragma unroll
        for (int b = 0; b < 4; ++b) acc[a][b] = 0.0f;

    for (int dc = 0; dc < 2; ++dc) {
        __syncthreads();
        #pragma unroll
        for (int rep = 0; rep < 4; ++rep) {
            int f = rep * 256 + t;
            int row = f >> 4;
            int c4  = f & 15;
            *(float4*)&s_q[row * SW + c4 * 4] =
                *(const float4*)&qkv[(n0 + row) * (3 * kHHD) + h * 384 + dc * 64 + c4 * 4];
            *(float4*)&s_k[row * SW + c4 * 4] =
                *(const float4*)&qkv[(m0 + row) * (3 * kHHD) + h * 384 + 128 + dc * 64 + c4 * 4];
        }
        __syncthreads();
        for (int d = 0; d < 64; d += 4) {
            float a[4][4], b[4][4];
            #pragma unroll
            for (int rr = 0; rr < 4; ++rr) ld4(a[rr], &s_q[(tY + 16 * rr) * SW + d]);
            #pragma unroll
            for (int cc = 0; cc < 4; ++cc) ld4(b[cc], &s_k[(tX + 16 * cc) * SW + d]);
            #pragma unroll
            for (int rr = 0; rr < 4; ++rr)
                #pragma unroll
                for (int cc = 0; cc < 4; ++cc)
                    #pragma unroll
                    for (int u = 0; u < 4; ++u)
                        acc[rr][cc] = fmaf(a[rr][u], b[cc][u], acc[rr][cc]);
        }
    }
    #pragma unroll
    for (int rr = 0; rr < 4; ++rr)
        #pragma unroll
        for (int cc = 0; cc < 4; ++cc) {
            int row = n0 + tY + 16 * rr;
            int col = m0 + tX + 16 * cc;
            long idx = (long)h * (kN * kN) + (long)row * kN + col;
            logits[idx] = acc[rr][cc] * kScale + diffs[idx];
        }
}

// ---------------- softmax over m, per (h,n) row ----------------
__global__ __launch_bounds__(256) void softmax_kernel(float* __restrict__ logits)
{
    const int row = blockIdx.x;
    float* p = logits + (long)row * kN;
    const int t = threadIdx.x;
    float v0 = p[t];
    float v1 = p[t + 256];
    float m = fmaxf(v0, v1);
    #pragma unroll
    for (int off = 32; off > 0; off >>= 1) m = fmaxf(m, __shfl_xor(m, off));
    __shared__ float s_red[4];
    __shared__ float s_sum[4];
    if ((t & 63) == 0) s_red[t >> 6] = m;
    __syncthreads();
    m = fmaxf(fmaxf(s_red[0], s_red[1]), fmaxf(s_red[2], s_red[3]));
    float e0 = expf(v0 - m);
    float e1 = expf(v1 - m);
    float s = e0 + e1;
    #pragma unroll
    for (int off = 32; off > 0; off >>= 1) s += __shfl_xor(s, off);
    if ((t & 63) == 0) s_sum[t >> 6] = s;
    __syncthreads();
    s = (s_sum[0] + s_sum[1]) + (s_sum[2] + s_sum[3]);
    float inv = 1.0f / s;
    p[t] = e0 * inv;
    p[t + 256] = e1 * inv;
}

// ---------------- vals[n, h*128+d] = sum_m attn[h,n,m]*v[m,h,d] ----------------
__global__ __launch_bounds__(256) void attnv_kernel(
    const float* __restrict__ attn, const float* __restrict__ qkv,
    float* __restrict__ vals)
{
    constexpr int SW = 68;
    __shared__ float s_p[64 * SW];
    __shared__ float s_v[64 * SW];
    const int t  = threadIdx.x;
    const int tx = t & 15;
    const int ty = t >> 4;
    const int h  = blockIdx.z;
    const int n0 = blockIdx.x * 64;
    const int d0 = blockIdx.y * 64;

    float acc[4][4];
    #pragma unroll
    for (int a = 0; a < 4; ++a)
        #pragma unroll
        for (int b = 0; b < 4; ++b) acc[a][b] = 0.0f;

    for (int mt = 0; mt < 8; ++mt) {
        const int m0 = mt * 64;
        __syncthreads();
        #pragma unroll
        for (int rep = 0; rep < 4; ++rep) {
            int f = rep * 256 + t;
            int row = f >> 4;
            int c4  = f & 15;
            *(float4*)&s_p[row * SW + c4 * 4] =
                *(const float4*)&attn[(long)h * (kN * kN) + (long)(n0 + row) * kN + m0 + c4 * 4];
            *(float4*)&s_v[row * SW + c4 * 4] =
                *(const float4*)&qkv[(m0 + row) * (3 * kHHD) + h * 384 + 256 + d0 + c4 * 4];
        }
        __syncthreads();
        for (int kk = 0; kk < 64; kk += 4) {
            float a[4][4], b[4][4];
            #pragma unroll
            for (int rr = 0; rr < 4; ++rr) ld4(a[rr], &s_p[(4 * ty + rr) * SW + kk]);
            #pragma unroll
            for (int u = 0; u < 4; ++u) ld4(b[u], &s_v[(kk + u) * SW + 4 * tx]);
            #pragma unroll
            for (int rr = 0; rr < 4; ++rr)
                #pragma unroll
                for (int cc = 0; cc < 4; ++cc)
                    #pragma unroll
                    for (int u = 0; u < 4; ++u)
                        acc[rr][cc] = fmaf(a[rr][u], b[u][cc], acc[rr][cc]);
        }
    }
    #pragma unroll
    for (int rr = 0; rr < 4; ++rr) {
        float4 o = make_float4(acc[rr][0], acc[rr][1], acc[rr][2], acc[rr][3]);
        *(float4*)&vals[(long)(n0 + 4 * ty + rr) * kHHD + h * kHD + d0 + 4 * tx] = o;
    }
}

// ---------------- x = LN2(x + vals@o_W + o_b) ----------------
__global__ __launch_bounds__(64) void oproj_ln_kernel(
    const float* __restrict__ vals, const float* __restrict__ o_W,
    const float* __restrict__ o_b, const float* __restrict__ g2,
    const float* __restrict__ b2, float* __restrict__ x)
{
    const int n = blockIdx.x;
    const int d = threadIdx.x;
    __shared__ float s_v[kHHD];
    #pragma unroll
    for (int r = 0; r < kHHD / kD; ++r) s_v[r * kD + d] = vals[n * kHHD + r * kD + d];
    __syncthreads();
    float acc = o_b[d];
    for (int j = 0; j < kHHD; ++j) acc = fmaf(s_v[j], o_W[j * kD + d], acc);
    float xv = x[n * kD + d] + acc;
    float mu = xv;
    #pragma unroll
    for (int off = 32; off > 0; off >>= 1) mu += __shfl_xor(mu, off);
    mu *= (1.0f / kD);
    float dv = xv - mu;
    float var = dv * dv;
    #pragma unroll
    for (int off = 32; off > 0; off >>= 1) var += __shfl_xor(var, off);
    var *= (1.0f / kD);
    x[n * kD + d] = dv * rsqrtf(var + kEps) * g2[d] + b2[d];
}

// ---------------- out = x @ out_W + out_b ----------------
__global__ __launch_bounds__(64) void final_kernel(
    const float* __restrict__ x, const float* __restrict__ out_W,
    const float* __restrict__ out_b, float* __restrict__ out)
{
    const int n = blockIdx.x * 64 + threadIdx.x;
    float acc = out_b[0];
    #pragma unroll
    for (int d = 0; d < kD; ++d) acc = fmaf(x[n * kD + d], out_W[d], acc);
    out[n] = acc;
}

} // anonymous namespace

extern "C" void kernel_launch(void* const* d_in, const int* in_sizes, int n_in,
                              void* d_out, int out_size, void* d_ws, size_t ws_size,
                              hipStream_t stream)
{
    (void)in_sizes; (void)n_in; (void)out_size; (void)ws_size;

    const float* nf     = (const float*)d_in[0];
    const float* amds   = (const float*)d_in[1];
    const float* emb_W  = (const float*)d_in[2];
    const float* emb_b  = (const float*)d_in[3];
    const float* bemb_W = (const float*)d_in[4];
    const float* bemb_b = (const float*)d_in[5];
    const float* ln1_g  = (const float*)d_in[6];
    const float* ln1_b  = (const float*)d_in[7];
    const float* ln2_g  = (const float*)d_in[8];
    const float* ln2_b  = (const float*)d_in[9];
    const float* qkv_W  = (const float*)d_in[10];
    const float* qkv_b  = (const float*)d_in[11];
    const float* diff_W = (const float*)d_in[12];
    const float* diff_b = (const float*)d_in[13];
    const float* o_W    = (const float*)d_in[14];
    const float* o_b    = (const float*)d_in[15];
    const float* bout_W = (const float*)d_in[16];
    const float* bout_b = (const float*)d_in[17];
    const float* out_W  = (const float*)d_in[18];
    const float* out_b  = (const float*)d_in[19];

    float* ws = (float*)d_ws;
    float* ws_x      = ws;                   // 512*64
    float* ws_b0     = ws_x + 32768;         // 512*64
    float* ws_qkv    = ws_b0 + 32768;        // 512*1536
    float* ws_vals   = ws_qkv + 786432;      // 512*512
    float* ws_diffs  = ws_vals + 262144;     // 4*512*512
    float* ws_logits = ws_diffs + 1048576;   // 4*512*512
    float* ws_bias   = ws_logits + 1048576;  // 512*512*64
    u16*   ws_u      = (u16*)(ws_bias + 16777216);
    u16* dWt_hi    = ws_u;                   // 4*512*64
    u16* dWt_lo    = dWt_hi + 131072;
    u16* boutWt_hi = dWt_lo + 131072;        // 4*64*512
    u16* boutWt_lo = boutWt_hi + 131072;

    embed_kernel<<<kN, kD, 0, stream>>>(nf, amds, emb_W, emb_b, bemb_W, bemb_b,
                                        ln1_g, ln1_b, ws_x, ws_b0);
    bias_init_kernel<<<(kN * kN * kD / 4) / 256, 256, 0, stream>>>(
        ws_b0, (float4*)ws_bias);
    prep_weights_kernel<<<(2 * 4 * 32768) / 256, 256, 0, stream>>>(
        diff_W, bout_W, dWt_hi, dWt_lo, boutWt_hi, boutWt_lo);

    for (int l = 0; l < 4; ++l) {
        qkv_kernel<<<dim3(6, kN), 256, 0, stream>>>(
            ws_x, qkv_W + l * kD * (3 * kHHD), qkv_b + l * (3 * kHHD), ws_qkv);
        bias_layer_mfma<<<kN * kN / 128, 256, 0, stream>>>(
            ws_bias, dWt_hi + l * 32768, dWt_lo + l * 32768,
            boutWt_hi + l * 32768, boutWt_lo + l * 32768,
            diff_b + l * kHHD, bout_b + l * kD, ws_diffs);
        logits_kernel<<<dim3(8, 8, kH), 256, 0, stream>>>(ws_qkv, ws_diffs, ws_logits);
        softmax_kernel<<<kH * kN, 256, 0, stream>>>(ws_logits);
        attnv_kernel<<<dim3(8, 2, kH), 256, 0, stream>>>(ws_logits, ws_qkv, ws_vals);
        oproj_ln_kernel<<<kN, kD, 0, stream>>>(
            ws_vals, o_W + l * kHHD * kD, o_b + l * kD, ln2_g, ln2_b, ws_x);
    }
    final_kernel<<<kN / kD, kD, 0, stream>>>(ws_x, out_W, out_b, (float*)d_out);
}

// Round 5
// 904.345 us; speedup vs baseline: 4.3016x; 1.0228x over previous
//
#include <hip/hip_runtime.h>
#include <hip/hip_bf16.h>
#include <cmath>

// CrAKN fused implementation.
// R5: bias chain moved to 32x32x16 MFMA (half the MFMA issue slots of R4's
// 16x16x32) with a re-derived W1^T row permutation so GEMM1's C registers ARE
// GEMM2's A-fragments (zero-LDS handoff preserved). attnv retiled to 128
// blocks. Everything else unchanged from R4.

namespace {

constexpr int kN   = 512;
constexpr int kD   = 64;
constexpr int kH   = 4;
constexpr int kHD  = 128;
constexpr int kHHD = 512;
constexpr int kFB  = 256;
constexpr int kK   = 100;
constexpr float kEps   = 1e-5f;
constexpr float kScale = 0.08838834764831845f; // 1/sqrt(128)

typedef unsigned short u16;
typedef unsigned int u32;
typedef short bf16x8 __attribute__((ext_vector_type(8)));
typedef float f32x4 __attribute__((ext_vector_type(4)));
typedef float f32x16 __attribute__((ext_vector_type(16)));

// mish(x) = x*tanh(softplus(x)) = x * n/(n+2), n = e*(e+2), e = exp(x).
__device__ __forceinline__ float mish_f(float x) {
    float e = __expf(fminf(x, 15.0f));
    float n = e * (e + 2.0f);
    return x * n * __builtin_amdgcn_rcpf(n + 2.0f);
}

__device__ __forceinline__ u32 pk_bf16(float a, float b) {
    union { __hip_bfloat162 v; u32 u; } cv;
    cv.v = __float22bfloat162_rn(make_float2(a, b));
    return cv.u; // a low 16, b high 16
}
__device__ __forceinline__ void split2(float a, float b, u32& hi, u32& lo) {
    hi = pk_bf16(a, b);
    float fa = __uint_as_float(hi << 16);
    float fb = __uint_as_float(hi & 0xFFFF0000u);
    lo = pk_bf16(a - fa, b - fb);
}
__device__ __forceinline__ bf16x8 mk8(u32 a, u32 b, u32 c, u32 d) {
    union { u32 w[4]; bf16x8 v; } cv;
    cv.w[0] = a; cv.w[1] = b; cv.w[2] = c; cv.w[3] = d;
    return cv.v;
}

__device__ __forceinline__ u16 bf16_rne(float f) {
    u32 u = __float_as_uint(f);
    u = u + 0x7FFFu + ((u >> 16) & 1u);
    return (u16)(u >> 16);
}
__device__ __forceinline__ void bf16_split(float f, u16& h, u16& l) {
    h = bf16_rne(f);
    float fh = __uint_as_float((u32)h << 16);
    l = bf16_rne(f - fh);
}

__device__ __forceinline__ void ld4(float* d, const float* s) {
    float4 v = *(const float4*)s;
    d[0] = v.x; d[1] = v.y; d[2] = v.z; d[3] = v.w;
}

// ---------------- embed + LN1, and b0 = amds @ bias_emb ----------------
__global__ __launch_bounds__(64) void embed_kernel(
    const float* __restrict__ nf, const float* __restrict__ amds,
    const float* __restrict__ emb_W, const float* __restrict__ emb_b,
    const float* __restrict__ bemb_W, const float* __restrict__ bemb_b,
    const float* __restrict__ ln1_g, const float* __restrict__ ln1_b,
    float* __restrict__ x, float* __restrict__ b0)
{
    const int n = blockIdx.x;
    const int d = threadIdx.x;
    __shared__ float s_row[kFB];
    #pragma unroll
    for (int r = 0; r < kFB / kD; ++r) s_row[r * kD + d] = nf[n * kFB + r * kD + d];
    __syncthreads();
    float acc = emb_b[d];
    for (int k = 0; k < kFB; ++k) acc = fmaf(s_row[k], emb_W[k * kD + d], acc);
    float mu = acc;
    #pragma unroll
    for (int off = 32; off > 0; off >>= 1) mu += __shfl_xor(mu, off);
    mu *= (1.0f / kD);
    float dv = acc - mu;
    float var = dv * dv;
    #pragma unroll
    for (int off = 32; off > 0; off >>= 1) var += __shfl_xor(var, off);
    var *= (1.0f / kD);
    x[n * kD + d] = dv * rsqrtf(var + kEps) * ln1_g[d] + ln1_b[d];
    __syncthreads();
    s_row[d] = amds[n * kK + d];
    if (d < kK - kD) s_row[kD + d] = amds[n * kK + kD + d];
    __syncthreads();
    float bacc = bemb_b[d];
    for (int k = 0; k < kK; ++k) bacc = fmaf(s_row[k], bemb_W[k * kD + d], bacc);
    b0[n * kD + d] = bacc;
}

// ---------------- bias[i,j,d] = b0[j,d] - b0[i,d] ----------------
__global__ __launch_bounds__(256) void bias_init_kernel(
    const float* __restrict__ b0, float4* __restrict__ bias)
{
    int gid = blockIdx.x * 256 + threadIdx.x;
    int d4 = gid & 15;
    int j  = (gid >> 4) & (kN - 1);
    int i  = gid >> 13;
    const float4* b4 = (const float4*)b0;
    float4 a = b4[j * 16 + d4];
    float4 c = b4[i * 16 + d4];
    bias[gid] = make_float4(a.x - c.x, a.y - c.y, a.z - c.z, a.w - c.w);
}

// ---------------- per-launch weight prep: transpose + bf16 hi/lo split ------
// dWt[l][n][k]  (n<512, k<64)  from diff_W[l][k][n]
// boutWt[l][d][k] (d<64, k<512) from bout_W[l][k][d]
__global__ __launch_bounds__(256) void prep_weights_kernel(
    const float* __restrict__ diff_W, const float* __restrict__ bout_W,
    u16* __restrict__ dWt_hi, u16* __restrict__ dWt_lo,
    u16* __restrict__ boutWt_hi, u16* __restrict__ boutWt_lo)
{
    int gid = blockIdx.x * 256 + threadIdx.x; // 2 * 4 * 32768
    if (gid < 4 * 32768) {
        int e = gid;
        int l = e >> 15;
        int r = e & 32767;
        int k = r >> 9;
        int n = r & 511;
        u16 h, lo;
        bf16_split(diff_W[e], h, lo);
        int w = l * 32768 + n * 64 + k;
        dWt_hi[w] = h; dWt_lo[w] = lo;
    } else {
        int e = gid - 4 * 32768;
        int l = e >> 15;
        int r = e & 32767;
        int k = r >> 6;
        int d = r & 63;
        u16 h, lo;
        bf16_split(bout_W[e], h, lo);
        int w = l * 32768 + d * 512 + k;
        boutWt_hi[w] = h; boutWt_lo[w] = lo;
    }
}

// ---------------- qkv = x @ qkv_W[l] + qkv_b[l] ----------------
__global__ __launch_bounds__(256) void qkv_kernel(
    const float* __restrict__ x, const float* __restrict__ W,
    const float* __restrict__ b, float* __restrict__ qkv)
{
    const int n = blockIdx.y;
    const int c = blockIdx.x * 256 + threadIdx.x;
    __shared__ float s_x[kD];
    if (threadIdx.x < kD) s_x[threadIdx.x] = x[n * kD + threadIdx.x];
    __syncthreads();
    float acc = b[c];
    #pragma unroll 8
    for (int d = 0; d < kD; ++d) acc = fmaf(s_x[d], W[d * (3 * kHHD) + c], acc);
    qkv[n * (3 * kHHD) + c] = acc;
}

// ---------------- fused pair-bias chain, MFMA bf16x3, 32x32x16 (v5) --------
// Block = 128 pairs (4 waves x 32). Per 32-becol chunk g2:
//   GEMM1 (be^T): A = W1^T with rows permuted p(k) = (k&3)+4*h(k)+8*g(k)+16*u(k)
//   so that C at lane (hw,ln) reg r holds be[pair=ln][k=16g+8hw+j] with
//   g=(r>>2)&1, j=(r&3)+4*((r>>3)&1) -- exactly GEMM2's 32x32x16 A-fragments
//   (g=0 <- regs {0..3,8..11}, g=1 <- regs {4..7,12..15}).
//   GEMM2: acc2[dt] += be @ W2. Zero-LDS handoff, 1 barrier/g2.
__global__ __launch_bounds__(256, 3) void bias_layer_mfma(
    float* __restrict__ bias,
    const u16* __restrict__ dWt_hi, const u16* __restrict__ dWt_lo,
    const u16* __restrict__ boutWt_hi, const u16* __restrict__ boutWt_lo,
    const float* __restrict__ diff_b, const float* __restrict__ bout_b,
    float* __restrict__ diffs)
{
    // [buf][plane][ w1: 32 rows * 64 u16 | w2 at 2048: 64 rows * 32 u16 ]
    __shared__ u16 s_w[2][2][4096]; // 32 KB

    const int t    = threadIdx.x;
    const int w    = t >> 6;
    const int lane = t & 63;
    const int hw   = lane >> 5;     // half-wave
    const int ln   = lane & 31;
    const int pb   = blockIdx.x * 128 + w * 32;  // wave's 32 pairs

    // --- staging indices: W1 row-permuted + 16B-granule XOR swizzle
    const int sb_bc  = t >> 3;       // source W1^T row (becol in chunk, 0..31)
    const int sb_kb  = t & 7;        // k granule (8 u16)
    const int sr     = (sb_bc & 3) + 4 * ((sb_bc >> 3) & 1)
                     + 8 * ((sb_bc >> 4) & 1) + 16 * ((sb_bc >> 2) & 1);
    const int w1_dst = sr * 64 + (sb_kb ^ (sr & 7)) * 8;
    const int sb_d   = t >> 2;       // W2 row d (0..63)
    const int sb_k2  = t & 3;        // k granule within 32
    const int w2_dst = 2048 + sb_d * 32 + (sb_k2 ^ ((sb_d >> 1) & 3)) * 8;
    const u16* g_w1h = dWt_hi + sb_bc * 64 + sb_kb * 8;
    const u16* g_w1l = dWt_lo + sb_bc * 64 + sb_kb * 8;
    const u16* g_w2h = boutWt_hi + sb_d * 512 + sb_k2 * 8;
    const u16* g_w2l = boutWt_lo + sb_d * 512 + sb_k2 * 8;

    // --- B1 frags: bias^T, K=64 in 4 K16-groups (kept in regs all loop)
    // B1[k = kg*16 + hw*8 + j][pair = ln]
    bf16x8 Bh[4], Bl[4];
    #pragma unroll
    for (int kg = 0; kg < 4; ++kg) {
        const float* src = bias + (long)(pb + ln) * kD + kg * 16 + hw * 8;
        float4 f0 = *(const float4*)src;
        float4 f1 = *(const float4*)(src + 4);
        u32 h0, l0, h1, l1, h2, l2, h3, l3;
        split2(f0.x, f0.y, h0, l0);
        split2(f0.z, f0.w, h1, l1);
        split2(f1.x, f1.y, h2, l2);
        split2(f1.z, f1.w, h3, l3);
        Bh[kg] = mk8(h0, h1, h2, h3);
        Bl[kg] = mk8(l0, l1, l2, l3);
    }

    // --- prologue stage g2=0 into buf 0
    {
        bf16x8 r0 = *(const bf16x8*)g_w1h;
        bf16x8 r1 = *(const bf16x8*)g_w1l;
        bf16x8 r2 = *(const bf16x8*)g_w2h;
        bf16x8 r3 = *(const bf16x8*)g_w2l;
        *(bf16x8*)&s_w[0][0][w1_dst] = r0;
        *(bf16x8*)&s_w[0][1][w1_dst] = r1;
        *(bf16x8*)&s_w[0][0][w2_dst] = r2;
        *(bf16x8*)&s_w[0][1][w2_dst] = r3;
    }
    __syncthreads();

    f32x16 acc2[2];
    acc2[0] = (f32x16)0.0f;
    acc2[1] = (f32x16)0.0f;
    float psum[4];
    #pragma unroll
    for (int h = 0; h < 4; ++h) psum[h] = 0.0f;

    const int sw1 = ln & 7;          // W1 read swizzle key (row = ln)
    const int sw2 = (ln >> 1) & 3;   // W2 read swizzle key
    int cur = 0;

    for (int g2 = 0; g2 < 16; ++g2) {
        // prefetch next weight chunk into regs (committed after compute)
        bf16x8 r0, r1, r2, r3;
        if (g2 < 15) {
            r0 = *(const bf16x8*)(g_w1h + (g2 + 1) * 2048);
            r1 = *(const bf16x8*)(g_w1l + (g2 + 1) * 2048);
            r2 = *(const bf16x8*)(g_w2h + (g2 + 1) * 32);
            r3 = *(const bf16x8*)(g_w2l + (g2 + 1) * 32);
        }

        // ---- GEMM1: a1 = W1^T(perm) x bias^T  (one 32x32 tile, K=64)
        f32x16 a1 = (f32x16)0.0f;
        const u16* w1h = &s_w[cur][0][0];
        const u16* w1l = &s_w[cur][1][0];
        #pragma unroll
        for (int kg = 0; kg < 4; ++kg) {
            int o = ln * 64 + ((kg * 2 + hw) ^ sw1) * 8;
            bf16x8 A_h = *(const bf16x8*)(w1h + o);
            bf16x8 A_l = *(const bf16x8*)(w1l + o);
            a1 = __builtin_amdgcn_mfma_f32_32x32x16_bf16(A_h, Bh[kg], a1, 0, 0, 0);
            a1 = __builtin_amdgcn_mfma_f32_32x32x16_bf16(A_l, Bh[kg], a1, 0, 0, 0);
            a1 = __builtin_amdgcn_mfma_f32_32x32x16_bf16(A_h, Bl[kg], a1, 0, 0, 0);
        }

        // ---- mish + psum + pack into GEMM2 A-frags
        // db for reg r: k = 8*hw + (r&3) + 4*((r>>3)&1) + 16*((r>>2)&1)
        const float* dbp = diff_b + g2 * 32 + hw * 8;
        float4 d0 = *(const float4*)(dbp);        // regs 0..3
        float4 d1 = *(const float4*)(dbp + 16);   // regs 4..7
        float4 d2 = *(const float4*)(dbp + 4);    // regs 8..11
        float4 d3 = *(const float4*)(dbp + 20);   // regs 12..15
        float v[16];
        v[0]  = mish_f(a1[0]  + d0.x);  v[1]  = mish_f(a1[1]  + d0.y);
        v[2]  = mish_f(a1[2]  + d0.z);  v[3]  = mish_f(a1[3]  + d0.w);
        v[4]  = mish_f(a1[4]  + d1.x);  v[5]  = mish_f(a1[5]  + d1.y);
        v[6]  = mish_f(a1[6]  + d1.z);  v[7]  = mish_f(a1[7]  + d1.w);
        v[8]  = mish_f(a1[8]  + d2.x);  v[9]  = mish_f(a1[9]  + d2.y);
        v[10] = mish_f(a1[10] + d2.z);  v[11] = mish_f(a1[11] + d2.w);
        v[12] = mish_f(a1[12] + d3.x);  v[13] = mish_f(a1[13] + d3.y);
        v[14] = mish_f(a1[14] + d3.z);  v[15] = mish_f(a1[15] + d3.w);
        const int hd = g2 >> 2;
        float ps = 0.0f;
        #pragma unroll
        for (int r = 0; r < 16; ++r) ps = fmaf(v[r], v[r], ps);
        psum[hd] += ps;
        // frag g=0 <- regs {0..3, 8..11}; g=1 <- regs {4..7, 12..15}
        u32 h01, l01, h23, l23, h89, l89, hAB, lAB;
        u32 h45, l45, h67, l67, hCD, lCD, hEF, lEF;
        split2(v[0], v[1], h01, l01);   split2(v[2], v[3], h23, l23);
        split2(v[8], v[9], h89, l89);   split2(v[10], v[11], hAB, lAB);
        split2(v[4], v[5], h45, l45);   split2(v[6], v[7], h67, l67);
        split2(v[12], v[13], hCD, lCD); split2(v[14], v[15], hEF, lEF);
        bf16x8 A2h[2], A2l[2];
        A2h[0] = mk8(h01, h23, h89, hAB);
        A2l[0] = mk8(l01, l23, l89, lAB);
        A2h[1] = mk8(h45, h67, hCD, hEF);
        A2l[1] = mk8(l45, l67, lCD, lEF);

        // ---- GEMM2: acc2[dt] += be @ W2 chunk (two 32-d tiles, K=32)
        const u16* w2h = &s_w[cur][0][2048];
        const u16* w2l = &s_w[cur][1][2048];
        #pragma unroll
        for (int dt = 0; dt < 2; ++dt) {
            #pragma unroll
            for (int g = 0; g < 2; ++g) {
                int o = (dt * 32 + ln) * 32 + ((g * 2 + hw) ^ sw2) * 8;
                bf16x8 Wh = *(const bf16x8*)(w2h + o);
                bf16x8 Wl = *(const bf16x8*)(w2l + o);
                acc2[dt] = __builtin_amdgcn_mfma_f32_32x32x16_bf16(A2h[g], Wh, acc2[dt], 0, 0, 0);
                acc2[dt] = __builtin_amdgcn_mfma_f32_32x32x16_bf16(A2l[g], Wh, acc2[dt], 0, 0, 0);
                acc2[dt] = __builtin_amdgcn_mfma_f32_32x32x16_bf16(A2h[g], Wl, acc2[dt], 0, 0, 0);
            }
        }

        // ---- commit prefetched chunk, flip buffers
        if (g2 < 15) {
            int nb = cur ^ 1;
            *(bf16x8*)&s_w[nb][0][w1_dst] = r0;
            *(bf16x8*)&s_w[nb][1][w1_dst] = r1;
            *(bf16x8*)&s_w[nb][0][w2_dst] = r2;
            *(bf16x8*)&s_w[nb][1][w2_dst] = r3;
            __syncthreads();
            cur = nb;
        }
    }

    // ---- epilogue: bias tile in place (D2 row = pair, col = d) + diffs
    #pragma unroll
    for (int dt = 0; dt < 2; ++dt) {
        float bb = bout_b[dt * 32 + ln];
        #pragma unroll
        for (int r = 0; r < 16; ++r) {
            int pair = (r & 3) + 8 * (r >> 2) + 4 * hw;
            float vv = mish_f(acc2[dt][r] + bb);
            bias[(long)(pb + pair) * kD + dt * 32 + ln] = vv;
        }
    }
    const int i  = blockIdx.x >> 2;
    const int jb = (blockIdx.x & 3) * 128 + w * 32;
    #pragma unroll
    for (int h2 = 0; h2 < 4; ++h2) {
        float s = psum[h2] + __shfl_xor(psum[h2], 32);
        if (hw == 0) diffs[h2 * (kN * kN) + i * kN + jb + ln] = sqrtf(s);
    }
}

// ---------------- logits[h,n,m] = scale*q.k + diffs ----------------
__global__ __launch_bounds__(256) void logits_kernel(
    const float* __restrict__ qkv, const float* __restrict__ diffs,
    float* __restrict__ logits)
{
    constexpr int SW = 68;
    __shared__ float s_q[64 * SW];
    __shared__ float s_k[64 * SW];
    const int t  = threadIdx.x;
    const int tX = t & 15;
    const int tY = t >> 4;
    const int h  = blockIdx.z;
    const int n0 = blockIdx.x * 64;
    const int m0 = blockIdx.y * 64;

    float acc[4][4];
    #pragma unroll
    for (int a = 0; a < 4; ++a)
        #pragma unroll
        for (int b = 0; b < 4; ++b) acc[a][b] = 0.0f;

    for (int dc = 0; dc < 2; ++dc) {
        __syncthreads();
        #pragma unroll
        for (int rep = 0; rep < 4; ++rep) {
            int f = rep * 256 + t;
            int row = f >> 4;
            int c4  = f & 15;
            *(float4*)&s_q[row * SW + c4 * 4] =
                *(const float4*)&qkv[(n0 + row) * (3 * kHHD) + h * 384 + dc * 64 + c4 * 4];
            *(float4*)&s_k[row * SW + c4 * 4] =
                *(const float4*)&qkv[(m0 + row) * (3 * kHHD) + h * 384 + 128 + dc * 64 + c4 * 4];
        }
        __syncthreads();
        for (int d = 0; d < 64; d += 4) {
            float a[4][4], b[4][4];
            #pragma unroll
            for (int rr = 0; rr < 4; ++rr) ld4(a[rr], &s_q[(tY + 16 * rr) * SW + d]);
            #pragma unroll
            for (int cc = 0; cc < 4; ++cc) ld4(b[cc], &s_k[(tX + 16 * cc) * SW + d]);
            #pragma unroll
            for (int rr = 0; rr < 4; ++rr)
                #pragma unroll
                for (int cc = 0; cc < 4; ++cc)
                    #pragma unroll
                    for (int u = 0; u < 4; ++u)
                        acc[rr][cc] = fmaf(a[rr][u], b[cc][u], acc[rr][cc]);
        }
    }
    #pragma unroll
    for (int rr = 0; rr < 4; ++rr)
        #pragma unroll
        for (int cc = 0; cc < 4; ++cc) {
            int row = n0 + tY + 16 * rr;
            int col = m0 + tX + 16 * cc;
            long idx = (long)h * (kN * kN) + (long)row * kN + col;
            logits[idx] = acc[rr][cc] * kScale + diffs[idx];
        }
}

// ---------------- softmax over m, per (h,n) row ----------------
__global__ __launch_bounds__(256) void softmax_kernel(float* __restrict__ logits)
{
    const int row = blockIdx.x;
    float* p = logits + (long)row * kN;
    const int t = threadIdx.x;
    float v0 = p[t];
    float v1 = p[t + 256];
    float m = fmaxf(v0, v1);
    #pragma unroll
    for (int off = 32; off > 0; off >>= 1) m = fmaxf(m, __shfl_xor(m, off));
    __shared__ float s_red[4];
    __shared__ float s_sum[4];
    if ((t & 63) == 0) s_red[t >> 6] = m;
    __syncthreads();
    m = fmaxf(fmaxf(s_red[0], s_red[1]), fmaxf(s_red[2], s_red[3]));
    float e0 = expf(v0 - m);
    float e1 = expf(v1 - m);
    float s = e0 + e1;
    #pragma unroll
    for (int off = 32; off > 0; off >>= 1) s += __shfl_xor(s, off);
    if ((t & 63) == 0) s_sum[t >> 6] = s;
    __syncthreads();
    s = (s_sum[0] + s_sum[1]) + (s_sum[2] + s_sum[3]);
    float inv = 1.0f / s;
    p[t] = e0 * inv;
    p[t + 256] = e1 * inv;
}

// ---------------- vals[n, h*128+d] = sum_m attn[h,n,m]*v[m,h,d] -------------
// R5: 32-row n-tiles -> 128 blocks (was 64).
__global__ __launch_bounds__(256) void attnv_kernel(
    const float* __restrict__ attn, const float* __restrict__ qkv,
    float* __restrict__ vals)
{
    constexpr int SW = 68;
    __shared__ float s_p[32 * SW];
    __shared__ float s_v[64 * SW];
    const int t  = threadIdx.x;
    const int tx = t & 15;
    const int ty = t >> 4;
    const int h  = blockIdx.z;
    const int n0 = blockIdx.x * 32;
    const int d0 = blockIdx.y * 64;

    float acc[2][4];
    #pragma unroll
    for (int a = 0; a < 2; ++a)
        #pragma unroll
        for (int b = 0; b < 4; ++b) acc[a][b] = 0.0f;

    for (int mt = 0; mt < 8; ++mt) {
        const int m0 = mt * 64;
        __syncthreads();
        #pragma unroll
        for (int rep = 0; rep < 2; ++rep) {
            int f = rep * 256 + t;   // 512 float4s of P
            int row = f >> 4;
            int c4  = f & 15;
            *(float4*)&s_p[row * SW + c4 * 4] =
                *(const float4*)&attn[(long)h * (kN * kN) + (long)(n0 + row) * kN + m0 + c4 * 4];
        }
        #pragma unroll
        for (int rep = 0; rep < 4; ++rep) {
            int f = rep * 256 + t;   // 1024 float4s of V
            int row = f >> 4;
            int c4  = f & 15;
            *(float4*)&s_v[row * SW + c4 * 4] =
                *(const float4*)&qkv[(m0 + row) * (3 * kHHD) + h * 384 + 256 + d0 + c4 * 4];
        }
        __syncthreads();
        for (int kk = 0; kk < 64; kk += 4) {
            float a[2][4], b[4][4];
            #pragma unroll
            for (int rr = 0; rr < 2; ++rr) ld4(a[rr], &s_p[(ty + 16 * rr) * SW + kk]);
            #pragma unroll
            for (int u = 0; u < 4; ++u) ld4(b[u], &s_v[(kk + u) * SW + 4 * tx]);
            #pragma unroll
            for (int rr = 0; rr < 2; ++rr)
                #pragma unroll
                for (int cc = 0; cc < 4; ++cc)
                    #pragma unroll
                    for (int u = 0; u < 4; ++u)
                        acc[rr][cc] = fmaf(a[rr][u], b[u][cc], acc[rr][cc]);
        }
    }
    #pragma unroll
    for (int rr = 0; rr < 2; ++rr) {
        float4 o = make_float4(acc[rr][0], acc[rr][1], acc[rr][2], acc[rr][3]);
        *(float4*)&vals[(long)(n0 + ty + 16 * rr) * kHHD + h * kHD + d0 + 4 * tx] = o;
    }
}

// ---------------- x = LN2(x + vals@o_W + o_b) ----------------
__global__ __launch_bounds__(64) void oproj_ln_kernel(
    const float* __restrict__ vals, const float* __restrict__ o_W,
    const float* __restrict__ o_b, const float* __restrict__ g2,
    const float* __restrict__ b2, float* __restrict__ x)
{
    const int n = blockIdx.x;
    const int d = threadIdx.x;
    __shared__ float s_v[kHHD];
    #pragma unroll
    for (int r = 0; r < kHHD / kD; ++r) s_v[r * kD + d] = vals[n * kHHD + r * kD + d];
    __syncthreads();
    float acc = o_b[d];
    for (int j = 0; j < kHHD; ++j) acc = fmaf(s_v[j], o_W[j * kD + d], acc);
    float xv = x[n * kD + d] + acc;
    float mu = xv;
    #pragma unroll
    for (int off = 32; off > 0; off >>= 1) mu += __shfl_xor(mu, off);
    mu *= (1.0f / kD);
    float dv = xv - mu;
    float var = dv * dv;
    #pragma unroll
    for (int off = 32; off > 0; off >>= 1) var += __shfl_xor(var, off);
    var *= (1.0f / kD);
    x[n * kD + d] = dv * rsqrtf(var + kEps) * g2[d] + b2[d];
}

// ---------------- out = x @ out_W + out_b ----------------
__global__ __launch_bounds__(64) void final_kernel(
    const float* __restrict__ x, const float* __restrict__ out_W,
    const float* __restrict__ out_b, float* __restrict__ out)
{
    const int n = blockIdx.x * 64 + threadIdx.x;
    float acc = out_b[0];
    #pragma unroll
    for (int d = 0; d < kD; ++d) acc = fmaf(x[n * kD + d], out_W[d], acc);
    out[n] = acc;
}

} // anonymous namespace

extern "C" void kernel_launch(void* const* d_in, const int* in_sizes, int n_in,
                              void* d_out, int out_size, void* d_ws, size_t ws_size,
                              hipStream_t stream)
{
    (void)in_sizes; (void)n_in; (void)out_size; (void)ws_size;

    const float* nf     = (const float*)d_in[0];
    const float* amds   = (const float*)d_in[1];
    const float* emb_W  = (const float*)d_in[2];
    const float* emb_b  = (const float*)d_in[3];
    const float* bemb_W = (const float*)d_in[4];
    const float* bemb_b = (const float*)d_in[5];
    const float* ln1_g  = (const float*)d_in[6];
    const float* ln1_b  = (const float*)d_in[7];
    const float* ln2_g  = (const float*)d_in[8];
    const float* ln2_b  = (const float*)d_in[9];
    const float* qkv_W  = (const float*)d_in[10];
    const float* qkv_b  = (const float*)d_in[11];
    const float* diff_W = (const float*)d_in[12];
    const float* diff_b = (const float*)d_in[13];
    const float* o_W    = (const float*)d_in[14];
    const float* o_b    = (const float*)d_in[15];
    const float* bout_W = (const float*)d_in[16];
    const float* bout_b = (const float*)d_in[17];
    const float* out_W  = (const float*)d_in[18];
    const float* out_b  = (const float*)d_in[19];

    float* ws = (float*)d_ws;
    float* ws_x      = ws;                   // 512*64
    float* ws_b0     = ws_x + 32768;         // 512*64
    float* ws_qkv    = ws_b0 + 32768;        // 512*1536
    float* ws_vals   = ws_qkv + 786432;      // 512*512
    float* ws_diffs  = ws_vals + 262144;     // 4*512*512
    float* ws_logits = ws_diffs + 1048576;   // 4*512*512
    float* ws_bias   = ws_logits + 1048576;  // 512*512*64
    u16*   ws_u      = (u16*)(ws_bias + 16777216);
    u16* dWt_hi    = ws_u;                   // 4*512*64
    u16* dWt_lo    = dWt_hi + 131072;
    u16* boutWt_hi = dWt_lo + 131072;        // 4*64*512
    u16* boutWt_lo = boutWt_hi + 131072;

    embed_kernel<<<kN, kD, 0, stream>>>(nf, amds, emb_W, emb_b, bemb_W, bemb_b,
                                        ln1_g, ln1_b, ws_x, ws_b0);
    bias_init_kernel<<<(kN * kN * kD / 4) / 256, 256, 0, stream>>>(
        ws_b0, (float4*)ws_bias);
    prep_weights_kernel<<<(2 * 4 * 32768) / 256, 256, 0, stream>>>(
        diff_W, bout_W, dWt_hi, dWt_lo, boutWt_hi, boutWt_lo);

    for (int l = 0; l < 4; ++l) {
        qkv_kernel<<<dim3(6, kN), 256, 0, stream>>>(
            ws_x, qkv_W + l * kD * (3 * kHHD), qkv_b + l * (3 * kHHD), ws_qkv);
        bias_layer_mfma<<<kN * kN / 128, 256, 0, stream>>>(
            ws_bias, dWt_hi + l * 32768, dWt_lo + l * 32768,
            boutWt_hi + l * 32768, boutWt_lo + l * 32768,
            diff_b + l * kHHD, bout_b + l * kD, ws_diffs);
        logits_kernel<<<dim3(8, 8, kH), 256, 0, stream>>>(ws_qkv, ws_diffs, ws_logits);
        softmax_kernel<<<kH * kN, 256, 0, stream>>>(ws_logits);
        attnv_kernel<<<dim3(16, 2, kH), 256, 0, stream>>>(ws_logits, ws_qkv, ws_vals);
        oproj_ln_kernel<<<kN, kD, 0, stream>>>(
            ws_vals, o_W + l * kHHD * kD, o_b + l * kD, ln2_g, ln2_b, ws_x);
    }
    final_kernel<<<kN / kD, kD, 0, stream>>>(ws_x, out_W, out_b, (float*)d_out);
}